// Round 10
// baseline (362.975 us; speedup 1.0000x reference)
//
#include <hip/hip_runtime.h>

// Dims: B=4, T=16, N=128, D=16, H=64, MH=128, 15 steps. NBLK=512 persistent blocks x 512 thr.
#define NBLK 512
#define CSCALE 2.8853900817779268f   // 2/ln2: tanh(x) = 1 - 2/(exp2(x*CSCALE)+1)

// ---- workspace float offsets ----
#define OFF_HS   0        // bf16 hs ping-pong: 2 * 65536 ushorts (PRESCALED by CSCALE)
#define OFF_PART 65536    // 512 mse partials
#define OFF_SYNC 66048    // 512 ints: flag[b][j] = last completed step+1 (monotonic)
#define OFF_BF   66560    // bf16 weights: 57344 ushorts

// ---- bf16 (ushort) offsets within bf area ----
#define BW2F  0        // W_msg2 B-frags (PRESCALED): 16*64*8 = 8192
#define BWIR  8192
#define BWII  9216
#define BWIN  10240
#define BWHR  11264    // HR|HI|HH contiguous 12288
#define BWHI  15360
#define BWHH  19456
#define BWO1  23552    // O1|O2|O3 contiguous 9216
#define BWO2  27648
#define BWO3  31744
#define BW1S  32768    // W1s | W1r : 16384
#define BW1RT 49152    // W1r TRANSPOSED [m][h]: 8192

#define INIT_TOTAL (32768 + 512 + 49152 + 8192)

typedef __attribute__((ext_vector_type(8))) __bf16 bf16x8;
typedef __attribute__((ext_vector_type(4))) float f32x4;
union frag_u { bf16x8 v; unsigned short s[8]; int4 q; };
union ldu { int4 q; unsigned short s[8]; unsigned u[4]; };

__device__ __forceinline__ unsigned short f2b(float x) {
  unsigned int u = __float_as_uint(x);
  u += 0x7fffu + ((u >> 16) & 1u);      // RNE (init only)
  return (unsigned short)(u >> 16);
}
__device__ __forceinline__ float b2f(unsigned short u) {
  return __uint_as_float(((unsigned int)u) << 16);
}
__device__ __forceinline__ float fast_tanh(float x) {        // raw-input tanh
  float e = __builtin_amdgcn_exp2f(x * CSCALE);
  return 1.0f - 2.0f * __builtin_amdgcn_rcpf(e + 1.0f);
}
__device__ __forceinline__ float tanh_pre(float x) {         // x already * CSCALE
  float e = __builtin_amdgcn_exp2f(x);
  return 1.0f - 2.0f * __builtin_amdgcn_rcpf(e + 1.0f);
}
__device__ __forceinline__ float fast_sigmoid(float x) {
  float e = __builtin_amdgcn_exp2f(x * -1.4426950408889634f);
  return __builtin_amdgcn_rcpf(1.0f + e);
}
// pack two floats -> bf16x2 (round-nearest ties-away) in ~3 VALU
__device__ __forceinline__ unsigned pack_bf2(float lo, float hi) {
  unsigned a = __float_as_uint(lo) + 0x8000u;
  unsigned b = __float_as_uint(hi) + 0x8000u;
  return __builtin_amdgcn_perm(b, a, 0x07060302u);  // {b.hi16, a.hi16}
}
__device__ __forceinline__ void st_coh_u32(unsigned* p, unsigned v) {
  __hip_atomic_store(p, v, __ATOMIC_RELAXED, __HIP_MEMORY_SCOPE_AGENT);
}
__device__ __forceinline__ void st_coh_i32(int* p, int v) {
  __hip_atomic_store(p, v, __ATOMIC_RELAXED, __HIP_MEMORY_SCOPE_AGENT);
}

// ---------------- init: hs0, flags, bf16 weight tables ----------------
__global__ void init_kernel(const float* __restrict__ W_msg2,
                            const float* __restrict__ W_ir, const float* __restrict__ W_ii,
                            const float* __restrict__ W_in,
                            const float* __restrict__ W_hr, const float* __restrict__ W_hi,
                            const float* __restrict__ W_hh,
                            const float* __restrict__ W_o1, const float* __restrict__ W_o2,
                            const float* __restrict__ W_o3,
                            const float* __restrict__ W_msg1, float* __restrict__ ws) {
  int idx = blockIdx.x * 256 + threadIdx.x;
  unsigned short* bw = (unsigned short*)(ws + OFF_BF);
  if (idx < 32768) { ws[OFF_HS + idx] = 0.0f; return; }   // hs parity-0 = 0 (bf16 zeros)
  idx -= 32768;
  if (idx < 512) { ((int*)(ws + OFF_SYNC))[idx] = 0; return; }  // flags
  idx -= 512;
  if (idx < 8192) {  // W_msg2 -> MFMA B-fragment order, PRESCALED by CSCALE
    int f = idx >> 9, l = (idx >> 3) & 63, jj = idx & 7;
    int kc = f >> 2, nt = f & 3;
    int k = kc * 32 + ((l >> 4) << 3) + jj;
    int n = (nt << 4) + (l & 15);
    bw[BW2F + idx] = f2b(W_msg2[k * 64 + n] * CSCALE);
    return;
  }
  idx -= 8192;
  if (idx < 1024) { bw[BWIR + idx] = f2b(W_ir[idx]); return; }
  idx -= 1024;
  if (idx < 1024) { bw[BWII + idx] = f2b(W_ii[idx]); return; }
  idx -= 1024;
  if (idx < 1024) { bw[BWIN + idx] = f2b(W_in[idx]); return; }
  idx -= 1024;
  if (idx < 4096) { bw[BWHR + idx] = f2b(W_hr[idx]); return; }
  idx -= 4096;
  if (idx < 4096) { bw[BWHI + idx] = f2b(W_hi[idx]); return; }
  idx -= 4096;
  if (idx < 4096) { bw[BWHH + idx] = f2b(W_hh[idx]); return; }
  idx -= 4096;
  if (idx < 4096) { bw[BWO1 + idx] = f2b(W_o1[idx]); return; }
  idx -= 4096;
  if (idx < 4096) { bw[BWO2 + idx] = f2b(W_o2[idx]); return; }
  idx -= 4096;
  if (idx < 1024) { bw[BWO3 + idx] = f2b(W_o3[idx]); return; }
  idx -= 1024;
  if (idx < 16384) { bw[BW1S + idx] = f2b(W_msg1[idx]); return; }  // W1s|W1r linear
  idx -= 16384;
  if (idx < 8192) {  // W1r transposed: bwt[m*64+h] = W_msg1[(64+h)*128+m]
    int m = idx >> 6, h = idx & 63;
    bw[BW1RT + idx] = f2b(W_msg1[(64 + h) * 128 + m]);
    return;
  }
}

// ---------------- persistent: 512 thr (8 waves); output MLP deferred to post-loop ----------------
__launch_bounds__(512, 4)
__global__ void step_all_kernel(const float* __restrict__ A, const float* __restrict__ X,
                                const float* __restrict__ b_msg1, const float* __restrict__ b_msg2,
                                const float* __restrict__ b_ir, const float* __restrict__ b_ii,
                                const float* __restrict__ b_in,
                                const float* __restrict__ b_o1, const float* __restrict__ b_o2,
                                const float* __restrict__ b_o3,
                                float* __restrict__ ws, float* __restrict__ out) {
  const int tid = threadIdx.x;
  const int bj = blockIdx.x;
  const int b = bj >> 7, j = bj & 127;
  const int wave = tid >> 6, lane = tid & 63;
  const unsigned short* bw = (const unsigned short*)(ws + OFF_BF);
  unsigned short* hs16 = (unsigned short*)(ws + OFF_HS);
  int* flags = (int*)(ws + OFF_SYNC);

  // [chunk][row] layouts: lane-stride 8 B -> conflict-free ds_read_b64
  __shared__ __align__(16) unsigned short lds_gate_t[12288]; // [g][c][h]4
  __shared__ __align__(16) unsigned short lds_w1t[8192];     // [c][m]4 (W1s)
  __shared__ __align__(16) unsigned short lds_outt[9216];    // O1[c][h]4|O2[c][h]4|O3[c][d]4
  __shared__ __align__(16) float sh_hr[128];   // hr row j, PRESCALED — block-private
  __shared__ __align__(16) float sh_Ar[128];
  __shared__ __align__(16) float sh_aggw[8][64];
  __shared__ __align__(16) float sh_agg[64];
  __shared__ __align__(16) float sh_xall[256]; // all 16 X rows for (b,j)
  __shared__ __align__(16) float sh_hid[64];
  __shared__ __align__(16) float sh_hist[960]; // hid history [t][h], t=0..14
  __shared__ __align__(16) float sh_pre[8][64];
  __shared__ int sh_w01;

  // ---- one-time staging (chunk-major transposes), 512-thread stride ----
  for (int i = tid; i < 12288; i += 512) {   // gates: [g][c][h][s] = W_g[4c+s][h]
    int g = i >> 12, r = i & 4095, c = r >> 8, rem = r & 255, h = rem >> 2, s = rem & 3;
    lds_gate_t[i] = bw[BWHR + (g << 12) + (((c << 2) + s) << 6) + h];
  }
  for (int i = tid; i < 8192; i += 512) {    // W1s: [c][m][s] = W1s[4c+s][m]
    int c = i >> 9, rem = i & 511, m = rem >> 2, s = rem & 3;
    lds_w1t[i] = bw[BW1S + (((c << 2) + s) << 7) + m];
  }
  for (int i = tid; i < 8192; i += 512) {    // O1,O2: [o][c][h][s]
    int o = i >> 12, r = i & 4095, c = r >> 8, rem = r & 255, h = rem >> 2, s = rem & 3;
    lds_outt[i] = bw[BWO1 + (o << 12) + (((c << 2) + s) << 6) + h];
  }
  for (int i = tid; i < 1024; i += 512) {    // O3: [c][d][s]
    int c = i >> 6, rem = i & 63, d = rem >> 2, s = rem & 3;
    lds_outt[8192 + i] = bw[BWO3 + (((c << 2) + s) << 4) + d];
  }
  if (tid < 256) {
    int t0 = tid >> 4, d = tid & 15;
    sh_xall[tid] = X[(((b << 4) + t0) << 11) + (j << 4) + d];
  }
  if (tid < 128) {
    float a1 = A[(b << 14) + (j << 7) + tid];
    float a2 = A[(b << 14) + (tid << 7) + j];
    float v = 0.5f * (a1 + a2);
    v = (tid == j) ? 0.0f : v;
    sh_Ar[tid] = fminf(fmaxf(v, 0.0f), 1.0f);
    sh_hr[tid] = b_msg1[tid] * CSCALE;            // hr_0 = b_msg1, prescaled
  } else if (tid < 192) {
    sh_hid[tid - 128] = 0.0f;
  }
  if (tid == 0) sh_w01 = 0;

  // persistent register state
  frag_u Bf[16];
  const int4* bw2 = (const int4*)bw;  // BW2F == 0
#pragma unroll
  for (int f = 0; f < 16; ++f) Bf[f].q = bw2[f * 64 + lane];
  float b2v[4];
#pragma unroll
  for (int nt = 0; nt < 4; ++nt) b2v[nt] = b_msg2[nt * 16 + (lane & 15)] * CSCALE;
  float my_bias = 0.0f;
  float wx[16];
  if (wave == 0 || wave == 1 || wave == 3) {
    my_bias = (wave == 0) ? b_ir[lane] : (wave == 1) ? b_ii[lane] : b_in[lane];
    const int xo = (wave == 0) ? BWIR : (wave == 1) ? BWII : BWIN;
#pragma unroll
    for (int d = 0; d < 16; ++d) wx[d] = b2f(bw[xo + d * 64 + lane]);
  }
  const float bm1a = b_msg1[lane], bm1b = b_msg1[lane + 64];
  const float bo1 = b_o1[lane], bo2 = b_o2[lane];
  const float bo3 = (lane < 16) ? b_o3[lane] : 0.0f;
  float macc = 0.0f;

  const int lane15 = lane & 15;
  const int k0 = (lane >> 4) << 3;
  __syncthreads();

  for (int t = 0; t < 15; ++t) {
    const int par = t & 1;
    const unsigned short* hs_cur = hs16 + par * 65536;
    unsigned short* hs_nxt = hs16 + (par ^ 1) * 65536;

    // ---- phase 2: one 16-row c-block per wave; coherent bf16 hs loads ----
    ldu va[4];
    {
      const unsigned short* p0 = hs_cur + (((b << 7) + (wave << 4) + lane15) << 7) + k0;
      asm volatile(
          "global_load_dwordx4 %0, %4, off sc0 sc1\n\t"
          "global_load_dwordx4 %1, %4, off offset:64 sc0 sc1\n\t"
          "global_load_dwordx4 %2, %4, off offset:128 sc0 sc1\n\t"
          "global_load_dwordx4 %3, %4, off offset:192 sc0 sc1\n\t"
          "s_waitcnt vmcnt(0)"
          : "=&v"(va[0].q), "=&v"(va[1].q), "=&v"(va[2].q), "=&v"(va[3].q)
          : "v"(p0)
          : "memory");
    }

    float part[4] = {0.f, 0.f, 0.f, 0.f};
    {
      f32x4 acc[4];
#pragma unroll
      for (int nt = 0; nt < 4; ++nt) acc[nt] = (f32x4){0.f, 0.f, 0.f, 0.f};
#pragma unroll
      for (int kc = 0; kc < 4; ++kc) {
        const ldu& u = va[kc];
        const float* hp = sh_hr + kc * 32 + k0;
        frag_u Af;
        int* ap = (int*)&Af.q;
#pragma unroll
        for (int p = 0; p < 4; ++p) {
          unsigned w = u.u[p];
          float x0 = __uint_as_float(w << 16) + hp[2 * p];        // prescaled sum
          float x1 = __uint_as_float(w & 0xffff0000u) + hp[2 * p + 1];
          ap[p] = (int)pack_bf2(tanh_pre(x0), tanh_pre(x1));
        }
#pragma unroll
        for (int nt = 0; nt < 4; ++nt)
          acc[nt] = __builtin_amdgcn_mfma_f32_16x16x32_bf16(Af.v, Bf[kc * 4 + nt].v, acc[nt], 0, 0, 0);
      }
      const int ibase = wave << 4;
      float4 aw = *(const float4*)(sh_Ar + ibase + ((lane >> 4) << 2));
#pragma unroll
      for (int r = 0; r < 4; ++r) {
        float wv = (r == 0) ? aw.x : (r == 1) ? aw.y : (r == 2) ? aw.z : aw.w;
#pragma unroll
        for (int nt = 0; nt < 4; ++nt)
          part[nt] += wv * tanh_pre(acc[nt][r] + b2v[nt]);   // acc,b2v prescaled
      }
    }
#pragma unroll
    for (int nt = 0; nt < 4; ++nt) {
      part[nt] += __shfl_xor(part[nt], 16);
      part[nt] += __shfl_xor(part[nt], 32);
    }
    if (lane < 16) {
#pragma unroll
      for (int nt = 0; nt < 4; ++nt) sh_aggw[wave][nt * 16 + lane] = part[nt];
    }
    __syncthreads();
    if (tid < 64) {
      float s = 0.0f;
#pragma unroll
      for (int w = 0; w < 8; ++w) s += sh_aggw[w][tid];
      sh_agg[tid] = s;
    }
    __syncthreads();

    // ---- phase 3a: gate matvecs on waves 0-3 (chunk-major rows, split accumulators) ----
    if (wave < 4) {
      float s = 0.0f;
      if (wave != 2) {
        s = my_bias;
        const float4* xr = (const float4*)(sh_xall + (t << 4));
#pragma unroll
        for (int c = 0; c < 4; ++c) {
          float4 xv = xr[c];
          s += xv.x * wx[4 * c] + xv.y * wx[4 * c + 1] + xv.z * wx[4 * c + 2] + xv.w * wx[4 * c + 3];
        }
      }
      if (wave != 3) {
        const ushort4* gp = ((const ushort4*)lds_gate_t) + (wave << 10) + lane;
        const float4* ag = (const float4*)sh_agg;
        float a0 = s, a1 = 0.f, a2 = 0.f, a3 = 0.f;
#pragma unroll
        for (int c = 0; c < 16; ++c) {
          ushort4 wv = gp[c << 6];
          float4 av = ag[c];
          a0 += av.x * b2f(wv.x); a1 += av.y * b2f(wv.y);
          a2 += av.z * b2f(wv.z); a3 += av.w * b2f(wv.w);
        }
        s = (a0 + a1) + (a2 + a3);
      }
      sh_pre[wave][lane] = s;
    }
    __syncthreads();
    if (tid < 64) {
      float r  = fast_sigmoid(sh_pre[0][tid]);
      float ig = fast_sigmoid(sh_pre[1][tid]);
      float n  = fast_tanh(sh_pre[3][tid] + r * sh_pre[2][tid]);
      float hnew = (1.0f - ig) * n + ig * sh_hid[tid];
      sh_hid[tid] = hnew;
      sh_hist[t * 64 + tid] = hnew;     // for post-loop MLP
    }
    __syncthreads();

    // ---- wave-specialized tail (t<14): hs / hr / poll(backoff) ----
    if (t < 14) {
      if (wave <= 1) {
        // next hs (cross-block): chunk-major W1s rows, prescaled output
        const int m = tid;  // 0..127
        const ushort4* wp = ((const ushort4*)lds_w1t) + m;
        const float4* h4 = (const float4*)sh_hid;
        float a0 = 0.f, a1 = 0.f, a2 = 0.f, a3 = 0.f;
#pragma unroll
        for (int c = 0; c < 16; ++c) {
          ushort4 wv = wp[c << 7];
          float4 hv = h4[c];
          a0 += hv.x * b2f(wv.x); a1 += hv.y * b2f(wv.y);
          a2 += hv.z * b2f(wv.z); a3 += hv.w * b2f(wv.w);
        }
        float s = ((a0 + a1) + (a2 + a3)) * CSCALE;
        float hi = __shfl_down(s, 1);
        if (!(lane & 1))
          st_coh_u32((unsigned*)hs_nxt + (bj << 6) + (m >> 1), pack_bf2(s, hi));
        asm volatile("s_waitcnt vmcnt(0)" ::: "memory");
        if (lane == 0) atomicAdd(&sh_w01, 1);
        if (wave == 0 && lane == 0) {
          const int tgt2 = 2 * (t + 1);
          while (__hip_atomic_load(&sh_w01, __ATOMIC_RELAXED, __HIP_MEMORY_SCOPE_WORKGROUP) < tgt2) {}
          st_coh_i32(flags + (b << 7) + j, t + 1);
        }
      } else if (wave == 2) {
        // next hr from transposed W1r in L2 (off critical path), prescaled
        const int4* wp1 = (const int4*)(bw + BW1RT + (lane << 6));
        const int4* wp2 = (const int4*)(bw + BW1RT + ((lane + 64) << 6));
        const float4* h4 = (const float4*)sh_hid;
        float s1a = bm1a, s1b = 0.f, s2a = bm1b, s2b = 0.f;
#pragma unroll
        for (int c = 0; c < 8; ++c) {
          ldu u1, u2; u1.q = wp1[c]; u2.q = wp2[c];
          float4 h0 = h4[2 * c], h1 = h4[2 * c + 1];
          s1a += h0.x * b2f(u1.s[0]); s1b += h0.y * b2f(u1.s[1]);
          s1a += h0.z * b2f(u1.s[2]); s1b += h0.w * b2f(u1.s[3]);
          s1a += h1.x * b2f(u1.s[4]); s1b += h1.y * b2f(u1.s[5]);
          s1a += h1.z * b2f(u1.s[6]); s1b += h1.w * b2f(u1.s[7]);
          s2a += h0.x * b2f(u2.s[0]); s2b += h0.y * b2f(u2.s[1]);
          s2a += h0.z * b2f(u2.s[2]); s2b += h0.w * b2f(u2.s[3]);
          s2a += h1.x * b2f(u2.s[4]); s2b += h1.y * b2f(u2.s[5]);
          s2a += h1.z * b2f(u2.s[6]); s2b += h1.w * b2f(u2.s[7]);
        }
        sh_hr[lane] = (s1a + s1b) * CSCALE;
        sh_hr[lane + 64] = (s2a + s2b) * CSCALE;
      } else if (wave == 3) {
        // poll with sleep backoff (cuts L3 interference vs tight loop)
        const int tgt = t + 1;
        const int* fp = flags + (b << 7) + (lane << 1);
        int2 fv;
        for (;;) {
          asm volatile("global_load_dwordx2 %0, %1, off sc0 sc1\n\ts_waitcnt vmcnt(0)"
                       : "=v"(fv) : "v"(fp) : "memory");
          if (!__any(fv.x < tgt || fv.y < tgt)) break;
          __builtin_amdgcn_s_sleep(2);
        }
      }
      // waves 4-7: idle until barrier
    }
    __syncthreads();
  }

  // ---- post-loop: deferred output MLP + pred + mse (8 waves, ~2 t each) ----
#pragma unroll
  for (int it = 0; it < 2; ++it) {
    const int tt = wave + (it << 3);
    if (tt >= 15) continue;  // wave-uniform
    const float4* h4 = (const float4*)(sh_hist + tt * 64);
    {
      const ushort4* r1 = ((const ushort4*)lds_outt) + lane;
      float a0 = bo1, a1 = 0.f, a2 = 0.f, a3 = 0.f;
#pragma unroll
      for (int c = 0; c < 16; ++c) {
        ushort4 wv = r1[c << 6]; float4 hv = h4[c];
        a0 += hv.x * b2f(wv.x); a1 += hv.y * b2f(wv.y);
        a2 += hv.z * b2f(wv.z); a3 += hv.w * b2f(wv.w);
      }
      sh_pre[wave][lane] = fmaxf((a0 + a1) + (a2 + a3), 0.0f);
    }
    {
      const ushort4* r2 = ((const ushort4*)lds_outt) + 1024 + lane;
      const float4* p4 = (const float4*)sh_pre[wave];
      float a0 = bo2, a1 = 0.f, a2 = 0.f, a3 = 0.f;
#pragma unroll
      for (int c = 0; c < 16; ++c) {
        ushort4 wv = r2[c << 6]; float4 pv = p4[c];
        a0 += pv.x * b2f(wv.x); a1 += pv.y * b2f(wv.y);
        a2 += pv.z * b2f(wv.z); a3 += pv.w * b2f(wv.w);
      }
      sh_aggw[wave][lane] = fmaxf((a0 + a1) + (a2 + a3), 0.0f);
    }
    if (lane < 16) {
      const ushort4* r3 = ((const ushort4*)lds_outt) + 2048 + lane;
      const float4* q4 = (const float4*)sh_aggw[wave];
      float a0 = bo3, a1 = 0.f, a2 = 0.f, a3 = 0.f;
#pragma unroll
      for (int c = 0; c < 16; ++c) {
        ushort4 wv = r3[c << 4]; float4 qv = q4[c];
        a0 += qv.x * b2f(wv.x); a1 += qv.y * b2f(wv.y);
        a2 += qv.z * b2f(wv.z); a3 += qv.w * b2f(wv.w);
      }
      float pred = sh_xall[(tt << 4) + lane] + (a0 + a1) + (a2 + a3);
      out[((b * 15 + tt) * 128 + j) * 16 + lane] = pred;
      float d = sh_xall[((tt + 1) << 4) + lane] - pred;
      macc += d * d;
    }
  }
  // mse partial reduce: lanes<16 per wave -> per block
  macc += __shfl_xor(macc, 1);
  macc += __shfl_xor(macc, 2);
  macc += __shfl_xor(macc, 4);
  macc += __shfl_xor(macc, 8);
  __syncthreads();
  if (lane == 0) sh_agg[wave] = macc;
  __syncthreads();
  if (tid == 0) {
    float s = 0.0f;
#pragma unroll
    for (int w = 0; w < 8; ++w) s += sh_agg[w];
    ws[OFF_PART + bj] = s;
  }
}

// ---------------- finalize: loglik ----------------
__global__ void final_kernel(const float* __restrict__ log_sigma, const float* __restrict__ ws,
                             float* __restrict__ out) {
  __shared__ float red[256];
  const int tid = threadIdx.x;
  red[tid] = ws[OFF_PART + tid] + ws[OFF_PART + 256 + tid];
  __syncthreads();
  if (tid == 0) {
    float mse = 0.0f;
    for (int i = 0; i < 256; ++i) mse += red[i];
    float sigma = expf(log_sigma[0]);
    float cst = 8192.0f * logf(sigma * sqrtf(6.2831853071795864f));  // N*D*B
    out[122880] = -(mse / (2.0f * sigma * sigma) + 15.0f * cst);
  }
}

extern "C" void kernel_launch(void* const* d_in, const int* in_sizes, int n_in,
                              void* d_out, int out_size, void* d_ws, size_t ws_size,
                              hipStream_t stream) {
  (void)in_sizes; (void)n_in; (void)out_size; (void)ws_size;
  const float* A      = (const float*)d_in[0];
  const float* X      = (const float*)d_in[1];
  const float* W_msg1 = (const float*)d_in[2];
  const float* b_msg1 = (const float*)d_in[3];
  const float* W_msg2 = (const float*)d_in[4];
  const float* b_msg2 = (const float*)d_in[5];
  const float* W_ir   = (const float*)d_in[6];
  const float* b_ir   = (const float*)d_in[7];
  const float* W_ii   = (const float*)d_in[8];
  const float* b_ii   = (const float*)d_in[9];
  const float* W_in   = (const float*)d_in[10];
  const float* b_in   = (const float*)d_in[11];
  const float* W_hr   = (const float*)d_in[12];
  const float* W_hi   = (const float*)d_in[13];
  const float* W_hh   = (const float*)d_in[14];
  const float* W_o1   = (const float*)d_in[15];
  const float* b_o1   = (const float*)d_in[16];
  const float* W_o2   = (const float*)d_in[17];
  const float* b_o2   = (const float*)d_in[18];
  const float* W_o3   = (const float*)d_in[19];
  const float* b_o3   = (const float*)d_in[20];
  const float* log_sigma = (const float*)d_in[21];
  float* ws  = (float*)d_ws;
  float* out = (float*)d_out;

  init_kernel<<<(INIT_TOTAL + 255) / 256, 256, 0, stream>>>(
      W_msg2, W_ir, W_ii, W_in, W_hr, W_hi, W_hh, W_o1, W_o2, W_o3, W_msg1, ws);
  step_all_kernel<<<NBLK, 512, 0, stream>>>(A, X, b_msg1, b_msg2, b_ir, b_ii, b_in,
                                            b_o1, b_o2, b_o3, ws, out);
  final_kernel<<<1, 256, 0, stream>>>(log_sigma, ws, out);
}

// Round 11
// 273.681 us; speedup vs baseline: 1.3263x; 1.3263x over previous
//
#include <hip/hip_runtime.h>

// Dims: B=4, T=16, N=128, D=16, H=64, MH=128, 15 steps. NBLK=512 persistent blocks.
#define NBLK 512
#define CSCALE 2.8853900817779268f   // 2/ln2: tanh(x) = 1 - 2/(exp2(x*CSCALE)+1)

// ---- workspace float offsets ----
#define OFF_HS   0        // bf16 hs ping-pong: 2 * 65536 ushorts (PRESCALED by CSCALE)
#define OFF_PART 65536    // 512 mse partials
#define OFF_SYNC 66048    // 512 ints: flag[b][j] = last completed step+1 (monotonic)
#define OFF_BF   66560    // bf16 weights: 57344 ushorts

// ---- bf16 (ushort) offsets within bf area ----
#define BW2F  0        // W_msg2 B-frags (PRESCALED): 16*64*8 = 8192
#define BWIR  8192
#define BWII  9216
#define BWIN  10240
#define BWHR  11264    // HR|HI|HH contiguous 12288
#define BWHI  15360
#define BWHH  19456
#define BWO1  23552    // O1|O2|O3 contiguous 9216
#define BWO2  27648
#define BWO3  31744
#define BW1S  32768    // W1s | W1r : 16384
#define BW1RT 49152    // W1r TRANSPOSED [m][h]: 8192

#define INIT_TOTAL (32768 + 512 + 49152 + 8192)

typedef __attribute__((ext_vector_type(8))) __bf16 bf16x8;
typedef __attribute__((ext_vector_type(4))) float f32x4;
union frag_u { bf16x8 v; unsigned short s[8]; int4 q; };
union ldu { int4 q; unsigned short s[8]; unsigned u[4]; };

__device__ __forceinline__ unsigned short f2b(float x) {
  unsigned int u = __float_as_uint(x);
  u += 0x7fffu + ((u >> 16) & 1u);      // RNE (init only)
  return (unsigned short)(u >> 16);
}
__device__ __forceinline__ float b2f(unsigned short u) {
  return __uint_as_float(((unsigned int)u) << 16);
}
__device__ __forceinline__ float fast_tanh(float x) {        // raw-input tanh
  float e = __builtin_amdgcn_exp2f(x * CSCALE);
  return 1.0f - 2.0f * __builtin_amdgcn_rcpf(e + 1.0f);
}
__device__ __forceinline__ float tanh_pre(float x) {         // x already * CSCALE
  float e = __builtin_amdgcn_exp2f(x);
  return 1.0f - 2.0f * __builtin_amdgcn_rcpf(e + 1.0f);
}
__device__ __forceinline__ float fast_sigmoid(float x) {
  float e = __builtin_amdgcn_exp2f(x * -1.4426950408889634f);
  return __builtin_amdgcn_rcpf(1.0f + e);
}
// pack two floats -> bf16x2 (round-nearest ties-away) in ~3 VALU
__device__ __forceinline__ unsigned pack_bf2(float lo, float hi) {
  unsigned a = __float_as_uint(lo) + 0x8000u;
  unsigned b = __float_as_uint(hi) + 0x8000u;
  return __builtin_amdgcn_perm(b, a, 0x07060302u);  // {b.hi16, a.hi16}
}
__device__ __forceinline__ void st_coh_u32(unsigned* p, unsigned v) {
  __hip_atomic_store(p, v, __ATOMIC_RELAXED, __HIP_MEMORY_SCOPE_AGENT);
}
__device__ __forceinline__ void st_coh_i32(int* p, int v) {
  __hip_atomic_store(p, v, __ATOMIC_RELAXED, __HIP_MEMORY_SCOPE_AGENT);
}

// ---------------- init: hs0, flags, bf16 weight tables ----------------
__global__ void init_kernel(const float* __restrict__ W_msg2,
                            const float* __restrict__ W_ir, const float* __restrict__ W_ii,
                            const float* __restrict__ W_in,
                            const float* __restrict__ W_hr, const float* __restrict__ W_hi,
                            const float* __restrict__ W_hh,
                            const float* __restrict__ W_o1, const float* __restrict__ W_o2,
                            const float* __restrict__ W_o3,
                            const float* __restrict__ W_msg1, float* __restrict__ ws) {
  int idx = blockIdx.x * 256 + threadIdx.x;
  unsigned short* bw = (unsigned short*)(ws + OFF_BF);
  if (idx < 32768) { ws[OFF_HS + idx] = 0.0f; return; }   // hs parity-0 = 0 (bf16 zeros)
  idx -= 32768;
  if (idx < 512) { ((int*)(ws + OFF_SYNC))[idx] = 0; return; }  // flags
  idx -= 512;
  if (idx < 8192) {  // W_msg2 -> MFMA B-fragment order, PRESCALED by CSCALE
    int f = idx >> 9, l = (idx >> 3) & 63, jj = idx & 7;
    int kc = f >> 2, nt = f & 3;
    int k = kc * 32 + ((l >> 4) << 3) + jj;
    int n = (nt << 4) + (l & 15);
    bw[BW2F + idx] = f2b(W_msg2[k * 64 + n] * CSCALE);
    return;
  }
  idx -= 8192;
  if (idx < 1024) { bw[BWIR + idx] = f2b(W_ir[idx]); return; }
  idx -= 1024;
  if (idx < 1024) { bw[BWII + idx] = f2b(W_ii[idx]); return; }
  idx -= 1024;
  if (idx < 1024) { bw[BWIN + idx] = f2b(W_in[idx]); return; }
  idx -= 1024;
  if (idx < 4096) { bw[BWHR + idx] = f2b(W_hr[idx]); return; }
  idx -= 4096;
  if (idx < 4096) { bw[BWHI + idx] = f2b(W_hi[idx]); return; }
  idx -= 4096;
  if (idx < 4096) { bw[BWHH + idx] = f2b(W_hh[idx]); return; }
  idx -= 4096;
  if (idx < 4096) { bw[BWO1 + idx] = f2b(W_o1[idx]); return; }
  idx -= 4096;
  if (idx < 4096) { bw[BWO2 + idx] = f2b(W_o2[idx]); return; }
  idx -= 4096;
  if (idx < 1024) { bw[BWO3 + idx] = f2b(W_o3[idx]); return; }
  idx -= 1024;
  if (idx < 16384) { bw[BW1S + idx] = f2b(W_msg1[idx]); return; }  // W1s|W1r linear
  idx -= 16384;
  if (idx < 8192) {  // W1r transposed: bwt[m*64+h] = W_msg1[(64+h)*128+m]
    int m = idx >> 6, h = idx & 63;
    bw[BW1RT + idx] = f2b(W_msg1[(64 + h) * 128 + m]);
    return;
  }
}

// ---------------- persistent: all 15 steps; output MLP deferred to post-loop ----------------
__launch_bounds__(256, 2)
__global__ void step_all_kernel(const float* __restrict__ A, const float* __restrict__ X,
                                const float* __restrict__ b_msg1, const float* __restrict__ b_msg2,
                                const float* __restrict__ b_ir, const float* __restrict__ b_ii,
                                const float* __restrict__ b_in,
                                const float* __restrict__ b_o1, const float* __restrict__ b_o2,
                                const float* __restrict__ b_o3,
                                float* __restrict__ ws, float* __restrict__ out) {
  const int tid = threadIdx.x;
  const int bj = blockIdx.x;
  const int b = bj >> 7, j = bj & 127;
  const int wave = tid >> 6, lane = tid & 63;
  const unsigned short* bw = (const unsigned short*)(ws + OFF_BF);
  unsigned short* hs16 = (unsigned short*)(ws + OFF_HS);
  int* flags = (int*)(ws + OFF_SYNC);

  // [chunk][row] layouts: lane-stride 8 B -> conflict-free ds_read_b64
  __shared__ __align__(16) unsigned short lds_gate_t[12288]; // [g][c][h]4
  __shared__ __align__(16) unsigned short lds_w1t[8192];     // [c][m]4 (W1s)
  __shared__ __align__(16) unsigned short lds_outt[9216];    // O1[c][h]4|O2[c][h]4|O3[c][d]4
  __shared__ __align__(16) float sh_hr[128];   // hr row j, PRESCALED — block-private
  __shared__ __align__(16) float sh_Ar[128];
  __shared__ __align__(16) float sh_aggw[4][64];
  __shared__ __align__(16) float sh_agg[64];
  __shared__ __align__(16) float sh_xall[256]; // all 16 X rows for (b,j)
  __shared__ __align__(16) float sh_hid[64];
  __shared__ __align__(16) float sh_hist[960]; // hid history [t][h], t=0..14
  __shared__ __align__(16) float sh_pre[4][64];
  __shared__ int sh_w01;

  // ---- one-time staging (chunk-major transposes) ----
  for (int i = tid; i < 12288; i += 256) {   // gates: [g][c][h][s] = W_g[4c+s][h]
    int g = i >> 12, r = i & 4095, c = r >> 8, rem = r & 255, h = rem >> 2, s = rem & 3;
    lds_gate_t[i] = bw[BWHR + (g << 12) + (((c << 2) + s) << 6) + h];
  }
  for (int i = tid; i < 8192; i += 256) {    // W1s: [c][m][s] = W1s[4c+s][m]
    int c = i >> 9, rem = i & 511, m = rem >> 2, s = rem & 3;
    lds_w1t[i] = bw[BW1S + (((c << 2) + s) << 7) + m];
  }
  for (int i = tid; i < 8192; i += 256) {    // O1,O2: [o][c][h][s]
    int o = i >> 12, r = i & 4095, c = r >> 8, rem = r & 255, h = rem >> 2, s = rem & 3;
    lds_outt[i] = bw[BWO1 + (o << 12) + (((c << 2) + s) << 6) + h];
  }
  for (int i = tid; i < 1024; i += 256) {    // O3: [c][d][s]
    int c = i >> 6, rem = i & 63, d = rem >> 2, s = rem & 3;
    lds_outt[8192 + i] = bw[BWO3 + (((c << 2) + s) << 4) + d];
  }
  {
    int t0 = tid >> 4, d = tid & 15;
    sh_xall[tid] = X[(((b << 4) + t0) << 11) + (j << 4) + d];
  }
  if (tid < 128) {
    float a1 = A[(b << 14) + (j << 7) + tid];
    float a2 = A[(b << 14) + (tid << 7) + j];
    float v = 0.5f * (a1 + a2);
    v = (tid == j) ? 0.0f : v;
    sh_Ar[tid] = fminf(fmaxf(v, 0.0f), 1.0f);
    sh_hr[tid] = b_msg1[tid] * CSCALE;            // hr_0 = b_msg1, prescaled
  } else if (tid < 192) {
    sh_hid[tid - 128] = 0.0f;
  }
  if (tid == 0) sh_w01 = 0;

  // persistent register state
  frag_u Bf[16];
  const int4* bw2 = (const int4*)bw;  // BW2F == 0
#pragma unroll
  for (int f = 0; f < 16; ++f) Bf[f].q = bw2[f * 64 + lane];
  float b2v[4];
#pragma unroll
  for (int nt = 0; nt < 4; ++nt) b2v[nt] = b_msg2[nt * 16 + (lane & 15)] * CSCALE;
  float my_bias = 0.0f;
  float wx[16];
  if (wave != 2) {
    my_bias = (wave == 0) ? b_ir[lane] : (wave == 1) ? b_ii[lane] : b_in[lane];
    const int xo = (wave == 0) ? BWIR : (wave == 1) ? BWII : BWIN;
#pragma unroll
    for (int d = 0; d < 16; ++d) wx[d] = b2f(bw[xo + d * 64 + lane]);
  }
  const float bm1a = b_msg1[lane], bm1b = b_msg1[lane + 64];
  const float bo1 = b_o1[lane], bo2 = b_o2[lane];
  const float bo3 = (lane < 16) ? b_o3[lane] : 0.0f;
  float macc = 0.0f;

  const int lane15 = lane & 15;
  const int k0 = (lane >> 4) << 3;
  __syncthreads();

  for (int t = 0; t < 15; ++t) {
    const int par = t & 1;
    const unsigned short* hs_cur = hs16 + par * 65536;
    unsigned short* hs_nxt = hs16 + (par ^ 1) * 65536;

    // ---- phase 2: coherent bf16 hs loads (single asm block, proven pattern) ----
    ldu va[8];
    {
      const unsigned short* p0 = hs_cur + (((b << 7) + (wave << 5) + lane15) << 7) + k0;
      const unsigned short* p1 = p0 + 2048;
      asm volatile(
          "global_load_dwordx4 %0, %8, off sc0 sc1\n\t"
          "global_load_dwordx4 %1, %8, off offset:64 sc0 sc1\n\t"
          "global_load_dwordx4 %2, %8, off offset:128 sc0 sc1\n\t"
          "global_load_dwordx4 %3, %8, off offset:192 sc0 sc1\n\t"
          "global_load_dwordx4 %4, %9, off sc0 sc1\n\t"
          "global_load_dwordx4 %5, %9, off offset:64 sc0 sc1\n\t"
          "global_load_dwordx4 %6, %9, off offset:128 sc0 sc1\n\t"
          "global_load_dwordx4 %7, %9, off offset:192 sc0 sc1\n\t"
          "s_waitcnt vmcnt(0)"
          : "=&v"(va[0].q), "=&v"(va[1].q), "=&v"(va[2].q), "=&v"(va[3].q),
            "=&v"(va[4].q), "=&v"(va[5].q), "=&v"(va[6].q), "=&v"(va[7].q)
          : "v"(p0), "v"(p1)
          : "memory");
    }

    float part[4] = {0.f, 0.f, 0.f, 0.f};
#pragma unroll
    for (int c = 0; c < 2; ++c) {
      f32x4 acc[4];
#pragma unroll
      for (int nt = 0; nt < 4; ++nt) acc[nt] = (f32x4){0.f, 0.f, 0.f, 0.f};
#pragma unroll
      for (int kc = 0; kc < 4; ++kc) {
        const ldu& u = va[c * 4 + kc];
        const float* hp = sh_hr + kc * 32 + k0;
        frag_u Af;
        int* ap = (int*)&Af.q;
#pragma unroll
        for (int p = 0; p < 4; ++p) {
          unsigned w = u.u[p];
          float x0 = __uint_as_float(w << 16) + hp[2 * p];        // prescaled sum
          float x1 = __uint_as_float(w & 0xffff0000u) + hp[2 * p + 1];
          ap[p] = (int)pack_bf2(tanh_pre(x0), tanh_pre(x1));
        }
#pragma unroll
        for (int nt = 0; nt < 4; ++nt)
          acc[nt] = __builtin_amdgcn_mfma_f32_16x16x32_bf16(Af.v, Bf[kc * 4 + nt].v, acc[nt], 0, 0, 0);
      }
      const int ibase = ((wave << 1) + c) << 4;
      float4 aw = *(const float4*)(sh_Ar + ibase + ((lane >> 4) << 2));
#pragma unroll
      for (int r = 0; r < 4; ++r) {
        float wv = (r == 0) ? aw.x : (r == 1) ? aw.y : (r == 2) ? aw.z : aw.w;
#pragma unroll
        for (int nt = 0; nt < 4; ++nt)
          part[nt] += wv * tanh_pre(acc[nt][r] + b2v[nt]);   // acc,b2v prescaled
      }
    }
#pragma unroll
    for (int nt = 0; nt < 4; ++nt) {
      part[nt] += __shfl_xor(part[nt], 16);
      part[nt] += __shfl_xor(part[nt], 32);
    }
    if (lane < 16) {
#pragma unroll
      for (int nt = 0; nt < 4; ++nt) sh_aggw[wave][nt * 16 + lane] = part[nt];
    }
    __syncthreads();
    if (tid < 64)
      sh_agg[tid] = sh_aggw[0][tid] + sh_aggw[1][tid] + sh_aggw[2][tid] + sh_aggw[3][tid];
    __syncthreads();

    // ---- phase 3a: gate matvecs (chunk-major rows, split accumulators) ----
    {
      float s = 0.0f;
      if (wave != 2) {
        s = my_bias;
        const float4* xr = (const float4*)(sh_xall + (t << 4));
#pragma unroll
        for (int c = 0; c < 4; ++c) {
          float4 xv = xr[c];
          s += xv.x * wx[4 * c] + xv.y * wx[4 * c + 1] + xv.z * wx[4 * c + 2] + xv.w * wx[4 * c + 3];
        }
      }
      if (wave != 3) {
        const ushort4* gp = ((const ushort4*)lds_gate_t) + (wave << 10) + lane;
        const float4* ag = (const float4*)sh_agg;
        float a0 = s, a1 = 0.f, a2 = 0.f, a3 = 0.f;
#pragma unroll
        for (int c = 0; c < 16; ++c) {
          ushort4 wv = gp[c << 6];
          float4 av = ag[c];
          a0 += av.x * b2f(wv.x); a1 += av.y * b2f(wv.y);
          a2 += av.z * b2f(wv.z); a3 += av.w * b2f(wv.w);
        }
        s = (a0 + a1) + (a2 + a3);
      }
      sh_pre[wave][lane] = s;
    }
    __syncthreads();
    if (tid < 64) {
      float r  = fast_sigmoid(sh_pre[0][tid]);
      float ig = fast_sigmoid(sh_pre[1][tid]);
      float n  = fast_tanh(sh_pre[3][tid] + r * sh_pre[2][tid]);
      float hnew = (1.0f - ig) * n + ig * sh_hid[tid];
      sh_hid[tid] = hnew;
      sh_hist[t * 64 + tid] = hnew;     // for post-loop MLP
    }
    __syncthreads();

    // ---- wave-specialized tail (t<14): hs+flag+poll(backoff) / hr ----
    if (t < 14) {
      if (wave <= 1) {
        // next hs (cross-block): chunk-major W1s rows, prescaled output
        const int m = tid;  // 0..127
        const ushort4* wp = ((const ushort4*)lds_w1t) + m;
        const float4* h4 = (const float4*)sh_hid;
        float a0 = 0.f, a1 = 0.f, a2 = 0.f, a3 = 0.f;
#pragma unroll
        for (int c = 0; c < 16; ++c) {
          ushort4 wv = wp[c << 7];
          float4 hv = h4[c];
          a0 += hv.x * b2f(wv.x); a1 += hv.y * b2f(wv.y);
          a2 += hv.z * b2f(wv.z); a3 += hv.w * b2f(wv.w);
        }
        float s = ((a0 + a1) + (a2 + a3)) * CSCALE;
        float hi = __shfl_down(s, 1);
        if (!(lane & 1))
          st_coh_u32((unsigned*)hs_nxt + (bj << 6) + (m >> 1), pack_bf2(s, hi));
        asm volatile("s_waitcnt vmcnt(0)" ::: "memory");  // hs stores at coherence point
        if (lane == 0) atomicAdd(&sh_w01, 1);
        if (wave == 0) {
          const int tgt = t + 1;
          if (lane == 0) {
            while (__hip_atomic_load(&sh_w01, __ATOMIC_RELAXED, __HIP_MEMORY_SCOPE_WORKGROUP) < 2 * tgt) {}
            st_coh_i32(flags + (b << 7) + j, tgt);  // single-store arrival
          }
          // whole wave polls all 128 flags AFTER producing (short window) w/ backoff
          const int* fp = flags + (b << 7) + (lane << 1);
          int2 fv;
          for (;;) {
            asm volatile("global_load_dwordx2 %0, %1, off sc0 sc1\n\ts_waitcnt vmcnt(0)"
                         : "=v"(fv) : "v"(fp) : "memory");
            if (!__any(fv.x < tgt || fv.y < tgt)) break;
            __builtin_amdgcn_s_sleep(1);
          }
        }
      } else if (wave == 2) {
        // next hr from transposed W1r in L2 (off critical path), prescaled
        const int4* wp1 = (const int4*)(bw + BW1RT + (lane << 6));
        const int4* wp2 = (const int4*)(bw + BW1RT + ((lane + 64) << 6));
        const float4* h4 = (const float4*)sh_hid;
        float s1a = bm1a, s1b = 0.f, s2a = bm1b, s2b = 0.f;
#pragma unroll
        for (int c = 0; c < 8; ++c) {
          ldu u1, u2; u1.q = wp1[c]; u2.q = wp2[c];
          float4 h0 = h4[2 * c], h1 = h4[2 * c + 1];
          s1a += h0.x * b2f(u1.s[0]); s1b += h0.y * b2f(u1.s[1]);
          s1a += h0.z * b2f(u1.s[2]); s1b += h0.w * b2f(u1.s[3]);
          s1a += h1.x * b2f(u1.s[4]); s1b += h1.y * b2f(u1.s[5]);
          s1a += h1.z * b2f(u1.s[6]); s1b += h1.w * b2f(u1.s[7]);
          s2a += h0.x * b2f(u2.s[0]); s2b += h0.y * b2f(u2.s[1]);
          s2a += h0.z * b2f(u2.s[2]); s2b += h0.w * b2f(u2.s[3]);
          s2a += h1.x * b2f(u2.s[4]); s2b += h1.y * b2f(u2.s[5]);
          s2a += h1.z * b2f(u2.s[6]); s2b += h1.w * b2f(u2.s[7]);
        }
        sh_hr[lane] = (s1a + s1b) * CSCALE;
        sh_hr[lane + 64] = (s2a + s2b) * CSCALE;
      }
      // wave 3: idle until barrier
    }
    __syncthreads();
  }

  // ---- post-loop: deferred output MLP + pred + mse (4 waves, ~4 t each) ----
#pragma unroll
  for (int it = 0; it < 4; ++it) {
    const int tt = wave + it * 4;
    if (tt >= 15) continue;  // wave-uniform
    const float4* h4 = (const float4*)(sh_hist + tt * 64);
    {
      const ushort4* r1 = ((const ushort4*)lds_outt) + lane;
      float a0 = bo1, a1 = 0.f, a2 = 0.f, a3 = 0.f;
#pragma unroll
      for (int c = 0; c < 16; ++c) {
        ushort4 wv = r1[c << 6]; float4 hv = h4[c];
        a0 += hv.x * b2f(wv.x); a1 += hv.y * b2f(wv.y);
        a2 += hv.z * b2f(wv.z); a3 += hv.w * b2f(wv.w);
      }
      sh_pre[wave][lane] = fmaxf((a0 + a1) + (a2 + a3), 0.0f);
    }
    {
      const ushort4* r2 = ((const ushort4*)lds_outt) + 1024 + lane;
      const float4* p4 = (const float4*)sh_pre[wave];
      float a0 = bo2, a1 = 0.f, a2 = 0.f, a3 = 0.f;
#pragma unroll
      for (int c = 0; c < 16; ++c) {
        ushort4 wv = r2[c << 6]; float4 pv = p4[c];
        a0 += pv.x * b2f(wv.x); a1 += pv.y * b2f(wv.y);
        a2 += pv.z * b2f(wv.z); a3 += pv.w * b2f(wv.w);
      }
      sh_aggw[wave][lane] = fmaxf((a0 + a1) + (a2 + a3), 0.0f);
    }
    if (lane < 16) {
      const ushort4* r3 = ((const ushort4*)lds_outt) + 2048 + lane;
      const float4* q4 = (const float4*)sh_aggw[wave];
      float a0 = bo3, a1 = 0.f, a2 = 0.f, a3 = 0.f;
#pragma unroll
      for (int c = 0; c < 16; ++c) {
        ushort4 wv = r3[c << 4]; float4 qv = q4[c];
        a0 += qv.x * b2f(wv.x); a1 += qv.y * b2f(wv.y);
        a2 += qv.z * b2f(wv.z); a3 += qv.w * b2f(wv.w);
      }
      float pred = sh_xall[(tt << 4) + lane] + (a0 + a1) + (a2 + a3);
      out[((b * 15 + tt) * 128 + j) * 16 + lane] = pred;
      float d = sh_xall[((tt + 1) << 4) + lane] - pred;
      macc += d * d;
    }
  }
  // mse partial reduce: lanes<16 per wave -> per block
  macc += __shfl_xor(macc, 1);
  macc += __shfl_xor(macc, 2);
  macc += __shfl_xor(macc, 4);
  macc += __shfl_xor(macc, 8);
  __syncthreads();
  if (lane == 0) sh_agg[wave] = macc;
  __syncthreads();
  if (tid == 0) ws[OFF_PART + bj] = sh_agg[0] + sh_agg[1] + sh_agg[2] + sh_agg[3];
}

// ---------------- finalize: loglik ----------------
__global__ void final_kernel(const float* __restrict__ log_sigma, const float* __restrict__ ws,
                             float* __restrict__ out) {
  __shared__ float red[256];
  const int tid = threadIdx.x;
  red[tid] = ws[OFF_PART + tid] + ws[OFF_PART + 256 + tid];
  __syncthreads();
  if (tid == 0) {
    float mse = 0.0f;
    for (int i = 0; i < 256; ++i) mse += red[i];
    float sigma = expf(log_sigma[0]);
    float cst = 8192.0f * logf(sigma * sqrtf(6.2831853071795864f));  // N*D*B
    out[122880] = -(mse / (2.0f * sigma * sigma) + 15.0f * cst);
  }
}

extern "C" void kernel_launch(void* const* d_in, const int* in_sizes, int n_in,
                              void* d_out, int out_size, void* d_ws, size_t ws_size,
                              hipStream_t stream) {
  (void)in_sizes; (void)n_in; (void)out_size; (void)ws_size;
  const float* A      = (const float*)d_in[0];
  const float* X      = (const float*)d_in[1];
  const float* W_msg1 = (const float*)d_in[2];
  const float* b_msg1 = (const float*)d_in[3];
  const float* W_msg2 = (const float*)d_in[4];
  const float* b_msg2 = (const float*)d_in[5];
  const float* W_ir   = (const float*)d_in[6];
  const float* b_ir   = (const float*)d_in[7];
  const float* W_ii   = (const float*)d_in[8];
  const float* b_ii   = (const float*)d_in[9];
  const float* W_in   = (const float*)d_in[10];
  const float* b_in   = (const float*)d_in[11];
  const float* W_hr   = (const float*)d_in[12];
  const float* W_hi   = (const float*)d_in[13];
  const float* W_hh   = (const float*)d_in[14];
  const float* W_o1   = (const float*)d_in[15];
  const float* b_o1   = (const float*)d_in[16];
  const float* W_o2   = (const float*)d_in[17];
  const float* b_o2   = (const float*)d_in[18];
  const float* W_o3   = (const float*)d_in[19];
  const float* b_o3   = (const float*)d_in[20];
  const float* log_sigma = (const float*)d_in[21];
  float* ws  = (float*)d_ws;
  float* out = (float*)d_out;

  init_kernel<<<(INIT_TOTAL + 255) / 256, 256, 0, stream>>>(
      W_msg2, W_ir, W_ii, W_in, W_hr, W_hi, W_hh, W_o1, W_o2, W_o3, W_msg1, ws);
  step_all_kernel<<<NBLK, 256, 0, stream>>>(A, X, b_msg1, b_msg2, b_ir, b_ii, b_in,
                                            b_o1, b_o2, b_o3, ws, out);
  final_kernel<<<1, 256, 0, stream>>>(log_sigma, ws, out);
}

// Round 12
// 246.855 us; speedup vs baseline: 1.4704x; 1.1087x over previous
//
#include <hip/hip_runtime.h>

// Dims: B=4, T=16, N=128, D=16, H=64, MH=128, 15 steps. NBLK=512 persistent blocks.
#define NBLK 512
#define CSCALE 2.8853900817779268f   // 2/ln2: tanh(x) = 1 - 2/(exp2(x*CSCALE)+1)

// ---- workspace float offsets ----
#define OFF_HS   0        // bf16 hs ping-pong: 2 * 65536 ushorts (PRESCALED by CSCALE)
#define OFF_PART 65536    // 512 mse partials
#define OFF_SYNC 66048    // 19200 ints: leaf[60*8]x32 | root[60]x32 | flag[60]x32
#define OFF_BF   85248    // bf16 weights: 57344 ushorts

// sync sub-offsets (ints, each slot stride 32 = 128B line)
#define SYNC_ROOT 15360
#define SYNC_FLAG 17280

// ---- bf16 (ushort) offsets within bf area ----
#define BW2F  0        // W_msg2 B-frags (PRESCALED): 16*64*8 = 8192
#define BWIR  8192
#define BWII  9216
#define BWIN  10240
#define BWHR  11264    // HR|HI|HH contiguous 12288
#define BWHI  15360
#define BWHH  19456
#define BWO1  23552    // O1|O2|O3 contiguous 9216
#define BWO2  27648
#define BWO3  31744
#define BW1S  32768    // W1s | W1r : 16384
#define BW1RT 49152    // W1r TRANSPOSED [m][h]: 8192

#define INIT_TOTAL (32768 + 19200 + 49152 + 8192)

typedef __attribute__((ext_vector_type(8))) __bf16 bf16x8;
typedef __attribute__((ext_vector_type(4))) float f32x4;
union frag_u { bf16x8 v; unsigned short s[8]; int4 q; };
union ldu { int4 q; unsigned short s[8]; unsigned u[4]; };

__device__ __forceinline__ unsigned short f2b(float x) {
  unsigned int u = __float_as_uint(x);
  u += 0x7fffu + ((u >> 16) & 1u);      // RNE (init only)
  return (unsigned short)(u >> 16);
}
__device__ __forceinline__ float b2f(unsigned short u) {
  return __uint_as_float(((unsigned int)u) << 16);
}
__device__ __forceinline__ float fast_tanh(float x) {        // raw-input tanh
  float e = __builtin_amdgcn_exp2f(x * CSCALE);
  return 1.0f - 2.0f * __builtin_amdgcn_rcpf(e + 1.0f);
}
__device__ __forceinline__ float tanh_pre(float x) {         // x already * CSCALE
  float e = __builtin_amdgcn_exp2f(x);
  return 1.0f - 2.0f * __builtin_amdgcn_rcpf(e + 1.0f);
}
__device__ __forceinline__ float fast_sigmoid(float x) {
  float e = __builtin_amdgcn_exp2f(x * -1.4426950408889634f);
  return __builtin_amdgcn_rcpf(1.0f + e);
}
// pack two floats -> bf16x2 (round-nearest ties-away) in ~3 VALU
__device__ __forceinline__ unsigned pack_bf2(float lo, float hi) {
  unsigned a = __float_as_uint(lo) + 0x8000u;
  unsigned b = __float_as_uint(hi) + 0x8000u;
  return __builtin_amdgcn_perm(b, a, 0x07060302u);  // {b.hi16, a.hi16}
}
__device__ __forceinline__ void st_coh_u32(unsigned* p, unsigned v) {
  __hip_atomic_store(p, v, __ATOMIC_RELAXED, __HIP_MEMORY_SCOPE_AGENT);
}
__device__ __forceinline__ void st_coh_i32(int* p, int v) {
  __hip_atomic_store(p, v, __ATOMIC_RELAXED, __HIP_MEMORY_SCOPE_AGENT);
}

// ---------------- init: hs0, sync slots, bf16 weight tables ----------------
__global__ void init_kernel(const float* __restrict__ W_msg2,
                            const float* __restrict__ W_ir, const float* __restrict__ W_ii,
                            const float* __restrict__ W_in,
                            const float* __restrict__ W_hr, const float* __restrict__ W_hi,
                            const float* __restrict__ W_hh,
                            const float* __restrict__ W_o1, const float* __restrict__ W_o2,
                            const float* __restrict__ W_o3,
                            const float* __restrict__ W_msg1, float* __restrict__ ws) {
  int idx = blockIdx.x * 256 + threadIdx.x;
  unsigned short* bw = (unsigned short*)(ws + OFF_BF);
  if (idx < 32768) { ws[OFF_HS + idx] = 0.0f; return; }   // hs parity-0 = 0 (bf16 zeros)
  idx -= 32768;
  if (idx < 19200) { ((int*)(ws + OFF_SYNC))[idx] = 0; return; }  // barrier slots
  idx -= 19200;
  if (idx < 8192) {  // W_msg2 -> MFMA B-fragment order, PRESCALED by CSCALE
    int f = idx >> 9, l = (idx >> 3) & 63, jj = idx & 7;
    int kc = f >> 2, nt = f & 3;
    int k = kc * 32 + ((l >> 4) << 3) + jj;
    int n = (nt << 4) + (l & 15);
    bw[BW2F + idx] = f2b(W_msg2[k * 64 + n] * CSCALE);
    return;
  }
  idx -= 8192;
  if (idx < 1024) { bw[BWIR + idx] = f2b(W_ir[idx]); return; }
  idx -= 1024;
  if (idx < 1024) { bw[BWII + idx] = f2b(W_ii[idx]); return; }
  idx -= 1024;
  if (idx < 1024) { bw[BWIN + idx] = f2b(W_in[idx]); return; }
  idx -= 1024;
  if (idx < 4096) { bw[BWHR + idx] = f2b(W_hr[idx]); return; }
  idx -= 4096;
  if (idx < 4096) { bw[BWHI + idx] = f2b(W_hi[idx]); return; }
  idx -= 4096;
  if (idx < 4096) { bw[BWHH + idx] = f2b(W_hh[idx]); return; }
  idx -= 4096;
  if (idx < 4096) { bw[BWO1 + idx] = f2b(W_o1[idx]); return; }
  idx -= 4096;
  if (idx < 4096) { bw[BWO2 + idx] = f2b(W_o2[idx]); return; }
  idx -= 4096;
  if (idx < 1024) { bw[BWO3 + idx] = f2b(W_o3[idx]); return; }
  idx -= 1024;
  if (idx < 16384) { bw[BW1S + idx] = f2b(W_msg1[idx]); return; }  // W1s|W1r linear
  idx -= 16384;
  if (idx < 8192) {  // W1r transposed: bwt[m*64+h] = W_msg1[(64+h)*128+m]
    int m = idx >> 6, h = idx & 63;
    bw[BW1RT + idx] = f2b(W_msg1[(64 + h) * 128 + m]);
    return;
  }
}

// ---------------- persistent: all 15 steps; output MLP deferred to post-loop ----------------
__launch_bounds__(256, 2)
__global__ void step_all_kernel(const float* __restrict__ A, const float* __restrict__ X,
                                const float* __restrict__ b_msg1, const float* __restrict__ b_msg2,
                                const float* __restrict__ b_ir, const float* __restrict__ b_ii,
                                const float* __restrict__ b_in,
                                const float* __restrict__ b_o1, const float* __restrict__ b_o2,
                                const float* __restrict__ b_o3,
                                float* __restrict__ ws, float* __restrict__ out) {
  const int tid = threadIdx.x;
  const int bj = blockIdx.x;
  // batch-aligned co-residency: blocks bj and bj+256 (same CU) get the SAME batch
  const int b = (bj >> 6) & 3;
  const int j = (bj & 63) | ((bj >> 8) << 6);
  const int row = (b << 7) + j;
  const int wave = tid >> 6, lane = tid & 63;
  const unsigned short* bw = (const unsigned short*)(ws + OFF_BF);
  unsigned short* hs16 = (unsigned short*)(ws + OFF_HS);
  int* sync = (int*)(ws + OFF_SYNC);

  // [chunk][row] layouts: lane-stride 8 B -> conflict-free ds_read_b64
  __shared__ __align__(16) unsigned short lds_gate_t[12288]; // [g][c][h]4
  __shared__ __align__(16) unsigned short lds_w1t[8192];     // [c][m]4 (W1s)
  __shared__ __align__(16) unsigned short lds_outt[9216];    // O1[c][h]4|O2[c][h]4|O3[c][d]4
  __shared__ __align__(16) float sh_hr[128];   // hr row j, PRESCALED — block-private
  __shared__ __align__(16) float sh_Ar[128];
  __shared__ __align__(16) float sh_aggw[4][64];
  __shared__ __align__(16) float sh_agg[64];
  __shared__ __align__(16) float sh_xall[256]; // all 16 X rows for (b,j)
  __shared__ __align__(16) float sh_hid[64];
  __shared__ __align__(16) float sh_hist[960]; // hid history [t][h], t=0..14
  __shared__ __align__(16) float sh_pre[4][64];
  __shared__ int sh_w01;

  // ---- one-time staging (chunk-major transposes) ----
  for (int i = tid; i < 12288; i += 256) {   // gates: [g][c][h][s] = W_g[4c+s][h]
    int g = i >> 12, r = i & 4095, c = r >> 8, rem = r & 255, h = rem >> 2, s = rem & 3;
    lds_gate_t[i] = bw[BWHR + (g << 12) + (((c << 2) + s) << 6) + h];
  }
  for (int i = tid; i < 8192; i += 256) {    // W1s: [c][m][s] = W1s[4c+s][m]
    int c = i >> 9, rem = i & 511, m = rem >> 2, s = rem & 3;
    lds_w1t[i] = bw[BW1S + (((c << 2) + s) << 7) + m];
  }
  for (int i = tid; i < 8192; i += 256) {    // O1,O2: [o][c][h][s]
    int o = i >> 12, r = i & 4095, c = r >> 8, rem = r & 255, h = rem >> 2, s = rem & 3;
    lds_outt[i] = bw[BWO1 + (o << 12) + (((c << 2) + s) << 6) + h];
  }
  for (int i = tid; i < 1024; i += 256) {    // O3: [c][d][s]
    int c = i >> 6, rem = i & 63, d = rem >> 2, s = rem & 3;
    lds_outt[8192 + i] = bw[BWO3 + (((c << 2) + s) << 4) + d];
  }
  {
    int t0 = tid >> 4, d = tid & 15;
    sh_xall[tid] = X[(((b << 4) + t0) << 11) + (j << 4) + d];
  }
  if (tid < 128) {
    float a1 = A[(b << 14) + (j << 7) + tid];
    float a2 = A[(b << 14) + (tid << 7) + j];
    float v = 0.5f * (a1 + a2);
    v = (tid == j) ? 0.0f : v;
    sh_Ar[tid] = fminf(fmaxf(v, 0.0f), 1.0f);
    sh_hr[tid] = b_msg1[tid] * CSCALE;            // hr_0 = b_msg1, prescaled
  } else if (tid < 192) {
    sh_hid[tid - 128] = 0.0f;
  }
  if (tid == 0) sh_w01 = 0;

  // persistent register state
  frag_u Bf[16];
  const int4* bw2 = (const int4*)bw;  // BW2F == 0
#pragma unroll
  for (int f = 0; f < 16; ++f) Bf[f].q = bw2[f * 64 + lane];
  float b2v[4];
#pragma unroll
  for (int nt = 0; nt < 4; ++nt) b2v[nt] = b_msg2[nt * 16 + (lane & 15)] * CSCALE;
  float my_bias = 0.0f;
  float wx[16];
  if (wave != 2) {
    my_bias = (wave == 0) ? b_ir[lane] : (wave == 1) ? b_ii[lane] : b_in[lane];
    const int xo = (wave == 0) ? BWIR : (wave == 1) ? BWII : BWIN;
#pragma unroll
    for (int d = 0; d < 16; ++d) wx[d] = b2f(bw[xo + d * 64 + lane]);
  }
  const float bm1a = b_msg1[lane], bm1b = b_msg1[lane + 64];
  const float bo1 = b_o1[lane], bo2 = b_o2[lane];
  const float bo3 = (lane < 16) ? b_o3[lane] : 0.0f;
  float macc = 0.0f;

  const int lane15 = lane & 15;
  const int k0 = (lane >> 4) << 3;
  __syncthreads();

  for (int t = 0; t < 15; ++t) {
    const int par = t & 1;
    const unsigned short* hs_cur = hs16 + par * 65536;
    unsigned short* hs_nxt = hs16 + (par ^ 1) * 65536;

    // ---- phase 2: coherent bf16 hs loads (single asm block, proven pattern) ----
    ldu va[8];
    {
      const unsigned short* p0 = hs_cur + (((b << 7) + (wave << 5) + lane15) << 7) + k0;
      const unsigned short* p1 = p0 + 2048;
      asm volatile(
          "global_load_dwordx4 %0, %8, off sc0 sc1\n\t"
          "global_load_dwordx4 %1, %8, off offset:64 sc0 sc1\n\t"
          "global_load_dwordx4 %2, %8, off offset:128 sc0 sc1\n\t"
          "global_load_dwordx4 %3, %8, off offset:192 sc0 sc1\n\t"
          "global_load_dwordx4 %4, %9, off sc0 sc1\n\t"
          "global_load_dwordx4 %5, %9, off offset:64 sc0 sc1\n\t"
          "global_load_dwordx4 %6, %9, off offset:128 sc0 sc1\n\t"
          "global_load_dwordx4 %7, %9, off offset:192 sc0 sc1\n\t"
          "s_waitcnt vmcnt(0)"
          : "=&v"(va[0].q), "=&v"(va[1].q), "=&v"(va[2].q), "=&v"(va[3].q),
            "=&v"(va[4].q), "=&v"(va[5].q), "=&v"(va[6].q), "=&v"(va[7].q)
          : "v"(p0), "v"(p1)
          : "memory");
    }

    float part[4] = {0.f, 0.f, 0.f, 0.f};
#pragma unroll
    for (int c = 0; c < 2; ++c) {
      f32x4 acc[4];
#pragma unroll
      for (int nt = 0; nt < 4; ++nt) acc[nt] = (f32x4){0.f, 0.f, 0.f, 0.f};
#pragma unroll
      for (int kc = 0; kc < 4; ++kc) {
        const ldu& u = va[c * 4 + kc];
        const float* hp = sh_hr + kc * 32 + k0;
        frag_u Af;
        int* ap = (int*)&Af.q;
#pragma unroll
        for (int p = 0; p < 4; ++p) {
          unsigned w = u.u[p];
          float x0 = __uint_as_float(w << 16) + hp[2 * p];        // prescaled sum
          float x1 = __uint_as_float(w & 0xffff0000u) + hp[2 * p + 1];
          ap[p] = (int)pack_bf2(tanh_pre(x0), tanh_pre(x1));
        }
#pragma unroll
        for (int nt = 0; nt < 4; ++nt)
          acc[nt] = __builtin_amdgcn_mfma_f32_16x16x32_bf16(Af.v, Bf[kc * 4 + nt].v, acc[nt], 0, 0, 0);
      }
      const int ibase = ((wave << 1) + c) << 4;
      float4 aw = *(const float4*)(sh_Ar + ibase + ((lane >> 4) << 2));
#pragma unroll
      for (int r = 0; r < 4; ++r) {
        float wv = (r == 0) ? aw.x : (r == 1) ? aw.y : (r == 2) ? aw.z : aw.w;
#pragma unroll
        for (int nt = 0; nt < 4; ++nt)
          part[nt] += wv * tanh_pre(acc[nt][r] + b2v[nt]);   // acc,b2v prescaled
      }
    }
#pragma unroll
    for (int nt = 0; nt < 4; ++nt) {
      part[nt] += __shfl_xor(part[nt], 16);
      part[nt] += __shfl_xor(part[nt], 32);
    }
    if (lane < 16) {
#pragma unroll
      for (int nt = 0; nt < 4; ++nt) sh_aggw[wave][nt * 16 + lane] = part[nt];
    }
    __syncthreads();
    if (tid < 64)
      sh_agg[tid] = sh_aggw[0][tid] + sh_aggw[1][tid] + sh_aggw[2][tid] + sh_aggw[3][tid];
    __syncthreads();

    // ---- phase 3a: gate matvecs (chunk-major rows, split accumulators) ----
    {
      float s = 0.0f;
      if (wave != 2) {
        s = my_bias;
        const float4* xr = (const float4*)(sh_xall + (t << 4));
#pragma unroll
        for (int c = 0; c < 4; ++c) {
          float4 xv = xr[c];
          s += xv.x * wx[4 * c] + xv.y * wx[4 * c + 1] + xv.z * wx[4 * c + 2] + xv.w * wx[4 * c + 3];
        }
      }
      if (wave != 3) {
        const ushort4* gp = ((const ushort4*)lds_gate_t) + (wave << 10) + lane;
        const float4* ag = (const float4*)sh_agg;
        float a0 = s, a1 = 0.f, a2 = 0.f, a3 = 0.f;
#pragma unroll
        for (int c = 0; c < 16; ++c) {
          ushort4 wv = gp[c << 6];
          float4 av = ag[c];
          a0 += av.x * b2f(wv.x); a1 += av.y * b2f(wv.y);
          a2 += av.z * b2f(wv.z); a3 += av.w * b2f(wv.w);
        }
        s = (a0 + a1) + (a2 + a3);
      }
      sh_pre[wave][lane] = s;
    }
    __syncthreads();
    if (tid < 64) {
      float r  = fast_sigmoid(sh_pre[0][tid]);
      float ig = fast_sigmoid(sh_pre[1][tid]);
      float n  = fast_tanh(sh_pre[3][tid] + r * sh_pre[2][tid]);
      float hnew = (1.0f - ig) * n + ig * sh_hid[tid];
      sh_hid[tid] = hnew;
      sh_hist[t * 64 + tid] = hnew;     // for post-loop MLP
    }
    __syncthreads();

    // ---- wave-specialized tail (t<14): hs+tree-barrier / hr ----
    if (t < 14) {
      if (wave <= 1) {
        // next hs (cross-block): chunk-major W1s rows, prescaled output
        const int m = tid;  // 0..127
        const ushort4* wp = ((const ushort4*)lds_w1t) + m;
        const float4* h4 = (const float4*)sh_hid;
        float a0 = 0.f, a1 = 0.f, a2 = 0.f, a3 = 0.f;
#pragma unroll
        for (int c = 0; c < 16; ++c) {
          ushort4 wv = wp[c << 7];
          float4 hv = h4[c];
          a0 += hv.x * b2f(wv.x); a1 += hv.y * b2f(wv.y);
          a2 += hv.z * b2f(wv.z); a3 += hv.w * b2f(wv.w);
        }
        float s = ((a0 + a1) + (a2 + a3)) * CSCALE;
        float hi = __shfl_down(s, 1);
        if (!(lane & 1))
          st_coh_u32((unsigned*)hs_nxt + (row << 6) + (m >> 1), pack_bf2(s, hi));
        asm volatile("s_waitcnt vmcnt(0)" ::: "memory");  // hs stores at coherence point
        if (lane == 0) atomicAdd(&sh_w01, 1);
        if (wave == 0 && lane == 0) {
          const int tgt = t + 1;
          while (__hip_atomic_load(&sh_w01, __ATOMIC_RELAXED, __HIP_MEMORY_SCOPE_WORKGROUP) < 2 * tgt) {}
          // tree barrier: leaf (16 arrivals) -> root (8) -> single flag; poll flag only
          const int bt = b * 15 + t;
          int* leaf = sync + ((bt << 3) + (j & 7)) * 32;
          int* root = sync + SYNC_ROOT + bt * 32;
          int* flag = sync + SYNC_FLAG + bt * 32;
          int r = __hip_atomic_fetch_add(leaf, 1, __ATOMIC_RELAXED, __HIP_MEMORY_SCOPE_AGENT);
          if (r == 15) {
            int r2 = __hip_atomic_fetch_add(root, 1, __ATOMIC_RELAXED, __HIP_MEMORY_SCOPE_AGENT);
            if (r2 == 7)
              __hip_atomic_store(flag, 1, __ATOMIC_RELAXED, __HIP_MEMORY_SCOPE_AGENT);
          }
          while (__hip_atomic_load(flag, __ATOMIC_RELAXED, __HIP_MEMORY_SCOPE_AGENT) == 0)
            __builtin_amdgcn_s_sleep(1);
        }
      } else if (wave == 2) {
        // next hr from transposed W1r in L2 (off critical path), prescaled
        const int4* wp1 = (const int4*)(bw + BW1RT + (lane << 6));
        const int4* wp2 = (const int4*)(bw + BW1RT + ((lane + 64) << 6));
        const float4* h4 = (const float4*)sh_hid;
        float s1a = bm1a, s1b = 0.f, s2a = bm1b, s2b = 0.f;
#pragma unroll
        for (int c = 0; c < 8; ++c) {
          ldu u1, u2; u1.q = wp1[c]; u2.q = wp2[c];
          float4 h0 = h4[2 * c], h1 = h4[2 * c + 1];
          s1a += h0.x * b2f(u1.s[0]); s1b += h0.y * b2f(u1.s[1]);
          s1a += h0.z * b2f(u1.s[2]); s1b += h0.w * b2f(u1.s[3]);
          s1a += h1.x * b2f(u1.s[4]); s1b += h1.y * b2f(u1.s[5]);
          s1a += h1.z * b2f(u1.s[6]); s1b += h1.w * b2f(u1.s[7]);
          s2a += h0.x * b2f(u2.s[0]); s2b += h0.y * b2f(u2.s[1]);
          s2a += h0.z * b2f(u2.s[2]); s2b += h0.w * b2f(u2.s[3]);
          s2a += h1.x * b2f(u2.s[4]); s2b += h1.y * b2f(u2.s[5]);
          s2a += h1.z * b2f(u2.s[6]); s2b += h1.w * b2f(u2.s[7]);
        }
        sh_hr[lane] = (s1a + s1b) * CSCALE;
        sh_hr[lane + 64] = (s2a + s2b) * CSCALE;
      }
      // wave 3: idle until barrier
    }
    __syncthreads();
  }

  // ---- post-loop: deferred output MLP + pred + mse (4 waves, ~4 t each) ----
#pragma unroll
  for (int it = 0; it < 4; ++it) {
    const int tt = wave + it * 4;
    if (tt >= 15) continue;  // wave-uniform
    const float4* h4 = (const float4*)(sh_hist + tt * 64);
    {
      const ushort4* r1 = ((const ushort4*)lds_outt) + lane;
      float a0 = bo1, a1 = 0.f, a2 = 0.f, a3 = 0.f;
#pragma unroll
      for (int c = 0; c < 16; ++c) {
        ushort4 wv = r1[c << 6]; float4 hv = h4[c];
        a0 += hv.x * b2f(wv.x); a1 += hv.y * b2f(wv.y);
        a2 += hv.z * b2f(wv.z); a3 += hv.w * b2f(wv.w);
      }
      sh_pre[wave][lane] = fmaxf((a0 + a1) + (a2 + a3), 0.0f);
    }
    {
      const ushort4* r2 = ((const ushort4*)lds_outt) + 1024 + lane;
      const float4* p4 = (const float4*)sh_pre[wave];
      float a0 = bo2, a1 = 0.f, a2 = 0.f, a3 = 0.f;
#pragma unroll
      for (int c = 0; c < 16; ++c) {
        ushort4 wv = r2[c << 6]; float4 pv = p4[c];
        a0 += pv.x * b2f(wv.x); a1 += pv.y * b2f(wv.y);
        a2 += pv.z * b2f(wv.z); a3 += pv.w * b2f(wv.w);
      }
      sh_aggw[wave][lane] = fmaxf((a0 + a1) + (a2 + a3), 0.0f);
    }
    if (lane < 16) {
      const ushort4* r3 = ((const ushort4*)lds_outt) + 2048 + lane;
      const float4* q4 = (const float4*)sh_aggw[wave];
      float a0 = bo3, a1 = 0.f, a2 = 0.f, a3 = 0.f;
#pragma unroll
      for (int c = 0; c < 16; ++c) {
        ushort4 wv = r3[c << 4]; float4 qv = q4[c];
        a0 += qv.x * b2f(wv.x); a1 += qv.y * b2f(wv.y);
        a2 += qv.z * b2f(wv.z); a3 += qv.w * b2f(wv.w);
      }
      float pred = sh_xall[(tt << 4) + lane] + (a0 + a1) + (a2 + a3);
      out[((b * 15 + tt) * 128 + j) * 16 + lane] = pred;
      float d = sh_xall[((tt + 1) << 4) + lane] - pred;
      macc += d * d;
    }
  }
  // mse partial reduce: lanes<16 per wave -> per block
  macc += __shfl_xor(macc, 1);
  macc += __shfl_xor(macc, 2);
  macc += __shfl_xor(macc, 4);
  macc += __shfl_xor(macc, 8);
  __syncthreads();
  if (lane == 0) sh_agg[wave] = macc;
  __syncthreads();
  if (tid == 0) ws[OFF_PART + bj] = sh_agg[0] + sh_agg[1] + sh_agg[2] + sh_agg[3];
}

// ---------------- finalize: loglik ----------------
__global__ void final_kernel(const float* __restrict__ log_sigma, const float* __restrict__ ws,
                             float* __restrict__ out) {
  __shared__ float red[256];
  const int tid = threadIdx.x;
  red[tid] = ws[OFF_PART + tid] + ws[OFF_PART + 256 + tid];
  __syncthreads();
  if (tid == 0) {
    float mse = 0.0f;
    for (int i = 0; i < 256; ++i) mse += red[i];
    float sigma = expf(log_sigma[0]);
    float cst = 8192.0f * logf(sigma * sqrtf(6.2831853071795864f));  // N*D*B
    out[122880] = -(mse / (2.0f * sigma * sigma) + 15.0f * cst);
  }
}

extern "C" void kernel_launch(void* const* d_in, const int* in_sizes, int n_in,
                              void* d_out, int out_size, void* d_ws, size_t ws_size,
                              hipStream_t stream) {
  (void)in_sizes; (void)n_in; (void)out_size; (void)ws_size;
  const float* A      = (const float*)d_in[0];
  const float* X      = (const float*)d_in[1];
  const float* W_msg1 = (const float*)d_in[2];
  const float* b_msg1 = (const float*)d_in[3];
  const float* W_msg2 = (const float*)d_in[4];
  const float* b_msg2 = (const float*)d_in[5];
  const float* W_ir   = (const float*)d_in[6];
  const float* b_ir   = (const float*)d_in[7];
  const float* W_ii   = (const float*)d_in[8];
  const float* b_ii   = (const float*)d_in[9];
  const float* W_in   = (const float*)d_in[10];
  const float* b_in   = (const float*)d_in[11];
  const float* W_hr   = (const float*)d_in[12];
  const float* W_hi   = (const float*)d_in[13];
  const float* W_hh   = (const float*)d_in[14];
  const float* W_o1   = (const float*)d_in[15];
  const float* b_o1   = (const float*)d_in[16];
  const float* W_o2   = (const float*)d_in[17];
  const float* b_o2   = (const float*)d_in[18];
  const float* W_o3   = (const float*)d_in[19];
  const float* b_o3   = (const float*)d_in[20];
  const float* log_sigma = (const float*)d_in[21];
  float* ws  = (float*)d_ws;
  float* out = (float*)d_out;

  init_kernel<<<(INIT_TOTAL + 255) / 256, 256, 0, stream>>>(
      W_msg2, W_ir, W_ii, W_in, W_hr, W_hi, W_hh, W_o1, W_o2, W_o3, W_msg1, ws);
  step_all_kernel<<<NBLK, 256, 0, stream>>>(A, X, b_msg1, b_msg2, b_ir, b_ii, b_in,
                                            b_o1, b_o2, b_o3, ws, out);
  final_kernel<<<1, 256, 0, stream>>>(log_sigma, ws, out);
}

// Round 13
// 244.357 us; speedup vs baseline: 1.4854x; 1.0102x over previous
//
#include <hip/hip_runtime.h>

// Dims: B=4, T=16, N=128, D=16, H=64, MH=128, 15 steps. NBLK=512 blocks x 512 thr.
#define NBLK 512
#define CSCALE 2.8853900817779268f   // 2/ln2: tanh(x) = 1 - 2/(exp2(x*CSCALE)+1)

// ---- workspace float offsets ----
#define OFF_HS   0        // bf16 hs ping-pong: 2 * 65536 ushorts (PRESCALED by CSCALE)
#define OFF_PART 65536    // 512 mse partials
#define OFF_SYNC 66048    // 19200 ints: leaf[60*8]x32 | root[60]x32 | flag[60]x32
#define OFF_BF   85248    // bf16 weights: 57344 ushorts

// sync sub-offsets (ints, each slot stride 32 = 128B line)
#define SYNC_ROOT 15360
#define SYNC_FLAG 17280

// ---- bf16 (ushort) offsets within bf area ----
#define BW2F  0        // W_msg2 B-frags (PRESCALED): 16*64*8 = 8192
#define BWIR  8192     // IR|II|IN contiguous 3072
#define BWII  9216
#define BWIN  10240
#define BWHR  11264    // HR|HI|HH contiguous 12288
#define BWHI  15360
#define BWHH  19456
#define BWO1  23552    // O1|O2|O3 contiguous 9216
#define BWO2  27648
#define BWO3  31744
#define BW1S  32768    // W1s | W1r : 16384
#define BW1RT 49152    // W1r TRANSPOSED [m][h]: 8192

#define INIT_TOTAL (32768 + 19200 + 49152 + 8192)

typedef __attribute__((ext_vector_type(8))) __bf16 bf16x8;
typedef __attribute__((ext_vector_type(4))) float f32x4;
union frag_u { bf16x8 v; unsigned short s[8]; int4 q; };
union ldu { int4 q; unsigned short s[8]; unsigned u[4]; };

__device__ __forceinline__ unsigned short f2b(float x) {
  unsigned int u = __float_as_uint(x);
  u += 0x7fffu + ((u >> 16) & 1u);      // RNE (init only)
  return (unsigned short)(u >> 16);
}
__device__ __forceinline__ float b2f(unsigned short u) {
  return __uint_as_float(((unsigned int)u) << 16);
}
__device__ __forceinline__ float fast_tanh(float x) {        // raw-input tanh
  float e = __builtin_amdgcn_exp2f(x * CSCALE);
  return 1.0f - 2.0f * __builtin_amdgcn_rcpf(e + 1.0f);
}
__device__ __forceinline__ float tanh_pre(float x) {         // x already * CSCALE
  float e = __builtin_amdgcn_exp2f(x);
  return 1.0f - 2.0f * __builtin_amdgcn_rcpf(e + 1.0f);
}
__device__ __forceinline__ float fast_sigmoid(float x) {
  float e = __builtin_amdgcn_exp2f(x * -1.4426950408889634f);
  return __builtin_amdgcn_rcpf(1.0f + e);
}
// pack two floats -> bf16x2 (round-nearest ties-away) in ~3 VALU
__device__ __forceinline__ unsigned pack_bf2(float lo, float hi) {
  unsigned a = __float_as_uint(lo) + 0x8000u;
  unsigned b = __float_as_uint(hi) + 0x8000u;
  return __builtin_amdgcn_perm(b, a, 0x07060302u);  // {b.hi16, a.hi16}
}
__device__ __forceinline__ void st_coh_u32(unsigned* p, unsigned v) {
  __hip_atomic_store(p, v, __ATOMIC_RELAXED, __HIP_MEMORY_SCOPE_AGENT);
}

// ---------------- init: hs0, sync slots, bf16 weight tables ----------------
__global__ void init_kernel(const float* __restrict__ W_msg2,
                            const float* __restrict__ W_ir, const float* __restrict__ W_ii,
                            const float* __restrict__ W_in,
                            const float* __restrict__ W_hr, const float* __restrict__ W_hi,
                            const float* __restrict__ W_hh,
                            const float* __restrict__ W_o1, const float* __restrict__ W_o2,
                            const float* __restrict__ W_o3,
                            const float* __restrict__ W_msg1, float* __restrict__ ws) {
  int idx = blockIdx.x * 256 + threadIdx.x;
  unsigned short* bw = (unsigned short*)(ws + OFF_BF);
  if (idx < 32768) { ws[OFF_HS + idx] = 0.0f; return; }   // hs parity-0 = 0 (bf16 zeros)
  idx -= 32768;
  if (idx < 19200) { ((int*)(ws + OFF_SYNC))[idx] = 0; return; }  // barrier slots
  idx -= 19200;
  if (idx < 8192) {  // W_msg2 -> MFMA B-fragment order, PRESCALED by CSCALE
    int f = idx >> 9, l = (idx >> 3) & 63, jj = idx & 7;
    int kc = f >> 2, nt = f & 3;
    int k = kc * 32 + ((l >> 4) << 3) + jj;
    int n = (nt << 4) + (l & 15);
    bw[BW2F + idx] = f2b(W_msg2[k * 64 + n] * CSCALE);
    return;
  }
  idx -= 8192;
  if (idx < 1024) { bw[BWIR + idx] = f2b(W_ir[idx]); return; }
  idx -= 1024;
  if (idx < 1024) { bw[BWII + idx] = f2b(W_ii[idx]); return; }
  idx -= 1024;
  if (idx < 1024) { bw[BWIN + idx] = f2b(W_in[idx]); return; }
  idx -= 1024;
  if (idx < 4096) { bw[BWHR + idx] = f2b(W_hr[idx]); return; }
  idx -= 4096;
  if (idx < 4096) { bw[BWHI + idx] = f2b(W_hi[idx]); return; }
  idx -= 4096;
  if (idx < 4096) { bw[BWHH + idx] = f2b(W_hh[idx]); return; }
  idx -= 4096;
  if (idx < 4096) { bw[BWO1 + idx] = f2b(W_o1[idx]); return; }
  idx -= 4096;
  if (idx < 4096) { bw[BWO2 + idx] = f2b(W_o2[idx]); return; }
  idx -= 4096;
  if (idx < 1024) { bw[BWO3 + idx] = f2b(W_o3[idx]); return; }
  idx -= 1024;
  if (idx < 16384) { bw[BW1S + idx] = f2b(W_msg1[idx]); return; }  // W1s|W1r linear
  idx -= 16384;
  if (idx < 8192) {  // W1r transposed: bwt[m*64+h] = W_msg1[(64+h)*128+m]
    int m = idx >> 6, h = idx & 63;
    bw[BW1RT + idx] = f2b(W_msg1[(64 + h) * 128 + m]);
    return;
  }
}

// ---------------- persistent: 512 thr / 8 waves; Bf + x-weights in LDS ----------------
__launch_bounds__(512, 4)
__global__ void step_all_kernel(const float* __restrict__ A, const float* __restrict__ X,
                                const float* __restrict__ b_msg1, const float* __restrict__ b_msg2,
                                const float* __restrict__ b_ir, const float* __restrict__ b_ii,
                                const float* __restrict__ b_in,
                                const float* __restrict__ b_o1, const float* __restrict__ b_o2,
                                const float* __restrict__ b_o3,
                                float* __restrict__ ws, float* __restrict__ out) {
  const int tid = threadIdx.x;
  const int bj = blockIdx.x;
  // batch-aligned co-residency: blocks bj and bj+256 (same CU) get the SAME batch
  const int b = (bj >> 6) & 3;
  const int j = (bj & 63) | ((bj >> 8) << 6);
  const int row = (b << 7) + j;
  const int wave = tid >> 6, lane = tid & 63;
  const unsigned short* bw = (const unsigned short*)(ws + OFF_BF);
  unsigned short* hs16 = (unsigned short*)(ws + OFF_HS);
  int* sync = (int*)(ws + OFF_SYNC);

  __shared__ __align__(16) unsigned short lds_bf[8192];      // W_msg2 B-frags (16 KB)
  __shared__ __align__(16) unsigned short lds_gate_t[12288]; // gates [g][c][h]4; O-weights post-loop
  __shared__ __align__(16) unsigned short lds_w1t[8192];     // W1s [c][m]4
  __shared__ __align__(16) unsigned short lds_xw[3072];      // IR|II|IN [g][d][h]
  __shared__ __align__(16) float sh_hr[128];
  __shared__ __align__(16) float sh_Ar[128];
  __shared__ __align__(16) float sh_aggw[8][64];
  __shared__ __align__(16) float sh_agg[64];
  __shared__ __align__(16) float sh_xall[256];
  __shared__ __align__(16) float sh_hid[64];
  __shared__ __align__(16) float sh_hist[960];
  __shared__ __align__(16) float sh_pre[8][64];
  __shared__ int sh_w01;

  // ---- one-time staging ----
  {
    const int4* src = (const int4*)bw;          // BW2F == 0: verbatim fragment order
    int4* dst = (int4*)lds_bf;
    for (int i = tid; i < 1024; i += 512) dst[i] = src[i];
  }
  for (int i = tid; i < 12288; i += 512) {   // gates: [g][c][h][s] = W_g[4c+s][h]
    int g = i >> 12, r = i & 4095, c = r >> 8, rem = r & 255, h = rem >> 2, s = rem & 3;
    lds_gate_t[i] = bw[BWHR + (g << 12) + (((c << 2) + s) << 6) + h];
  }
  for (int i = tid; i < 8192; i += 512) {    // W1s: [c][m][s] = W1s[4c+s][m]
    int c = i >> 9, rem = i & 511, m = rem >> 2, s = rem & 3;
    lds_w1t[i] = bw[BW1S + (((c << 2) + s) << 7) + m];
  }
  for (int i = tid; i < 3072; i += 512) lds_xw[i] = bw[BWIR + i];  // [g][d][h] natural
  if (tid < 256) {
    int t0 = tid >> 4, d = tid & 15;
    sh_xall[tid] = X[(((b << 4) + t0) << 11) + (j << 4) + d];
  }
  if (tid < 128) {
    float a1 = A[(b << 14) + (j << 7) + tid];
    float a2 = A[(b << 14) + (tid << 7) + j];
    float v = 0.5f * (a1 + a2);
    v = (tid == j) ? 0.0f : v;
    sh_Ar[tid] = fminf(fmaxf(v, 0.0f), 1.0f);
    sh_hr[tid] = b_msg1[tid] * CSCALE;
  } else if (tid < 192) {
    sh_hid[tid - 128] = 0.0f;
  }
  if (tid == 0) sh_w01 = 0;

  float b2v[4];
#pragma unroll
  for (int nt = 0; nt < 4; ++nt) b2v[nt] = b_msg2[nt * 16 + (lane & 15)] * CSCALE;
  float my_bias = 0.0f;
  if (wave == 0) my_bias = b_ir[lane];
  else if (wave == 1) my_bias = b_ii[lane];
  else if (wave == 3) my_bias = b_in[lane];
  const float bm1a = b_msg1[lane], bm1b = b_msg1[lane + 64];
  const float bo1 = b_o1[lane], bo2 = b_o2[lane];
  const float bo3 = (lane < 16) ? b_o3[lane] : 0.0f;
  float macc = 0.0f;

  const int lane15 = lane & 15;
  const int k0 = (lane >> 4) << 3;
  __syncthreads();

  for (int t = 0; t < 15; ++t) {
    const int par = t & 1;
    const unsigned short* hs_cur = hs16 + par * 65536;
    unsigned short* hs_nxt = hs16 + (par ^ 1) * 65536;

    // ---- phase 2: one 16-row c-block per wave; coherent bf16 hs loads ----
    ldu va[4];
    {
      const unsigned short* p0 = hs_cur + (((b << 7) + (wave << 4) + lane15) << 7) + k0;
      asm volatile(
          "global_load_dwordx4 %0, %4, off sc0 sc1\n\t"
          "global_load_dwordx4 %1, %4, off offset:64 sc0 sc1\n\t"
          "global_load_dwordx4 %2, %4, off offset:128 sc0 sc1\n\t"
          "global_load_dwordx4 %3, %4, off offset:192 sc0 sc1\n\t"
          "s_waitcnt vmcnt(0)"
          : "=&v"(va[0].q), "=&v"(va[1].q), "=&v"(va[2].q), "=&v"(va[3].q)
          : "v"(p0)
          : "memory");
    }

    float part[4] = {0.f, 0.f, 0.f, 0.f};
    {
      f32x4 acc[4];
#pragma unroll
      for (int nt = 0; nt < 4; ++nt) acc[nt] = (f32x4){0.f, 0.f, 0.f, 0.f};
#pragma unroll
      for (int kc = 0; kc < 4; ++kc) {
        const ldu& u = va[kc];
        const float* hp = sh_hr + kc * 32 + k0;
        frag_u Af;
        int* ap = (int*)&Af.q;
#pragma unroll
        for (int p = 0; p < 4; ++p) {
          unsigned w = u.u[p];
          float x0 = __uint_as_float(w << 16) + hp[2 * p];
          float x1 = __uint_as_float(w & 0xffff0000u) + hp[2 * p + 1];
          ap[p] = (int)pack_bf2(tanh_pre(x0), tanh_pre(x1));
        }
#pragma unroll
        for (int nt = 0; nt < 4; ++nt) {
          frag_u Bfr;
          Bfr.q = *(((const int4*)lds_bf) + (((kc << 2) + nt) << 6) + lane);
          acc[nt] = __builtin_amdgcn_mfma_f32_16x16x32_bf16(Af.v, Bfr.v, acc[nt], 0, 0, 0);
        }
      }
      const int ibase = wave << 4;
      float4 aw = *(const float4*)(sh_Ar + ibase + ((lane >> 4) << 2));
#pragma unroll
      for (int r = 0; r < 4; ++r) {
        float wv = (r == 0) ? aw.x : (r == 1) ? aw.y : (r == 2) ? aw.z : aw.w;
#pragma unroll
        for (int nt = 0; nt < 4; ++nt)
          part[nt] += wv * tanh_pre(acc[nt][r] + b2v[nt]);
      }
    }
#pragma unroll
    for (int nt = 0; nt < 4; ++nt) {
      part[nt] += __shfl_xor(part[nt], 16);
      part[nt] += __shfl_xor(part[nt], 32);
    }
    if (lane < 16) {
#pragma unroll
      for (int nt = 0; nt < 4; ++nt) sh_aggw[wave][nt * 16 + lane] = part[nt];
    }
    __syncthreads();
    if (tid < 64) {
      float s = 0.0f;
#pragma unroll
      for (int w = 0; w < 8; ++w) s += sh_aggw[w][tid];
      sh_agg[tid] = s;
    }
    __syncthreads();

    // ---- phase 3a: gate matvecs on waves 0-3 ----
    if (wave < 4) {
      float s = 0.0f;
      if (wave != 2) {
        s = my_bias;
        const int g = (wave == 3) ? 2 : wave;
        const float* xr = sh_xall + (t << 4);
#pragma unroll
        for (int d = 0; d < 16; ++d) s += xr[d] * b2f(lds_xw[(g << 10) + (d << 6) + lane]);
      }
      if (wave != 3) {
        const ushort4* gp = ((const ushort4*)lds_gate_t) + (wave << 10) + lane;
        const float4* ag = (const float4*)sh_agg;
        float a0 = s, a1 = 0.f, a2 = 0.f, a3 = 0.f;
#pragma unroll
        for (int c = 0; c < 16; ++c) {
          ushort4 wv = gp[c << 6];
          float4 av = ag[c];
          a0 += av.x * b2f(wv.x); a1 += av.y * b2f(wv.y);
          a2 += av.z * b2f(wv.z); a3 += av.w * b2f(wv.w);
        }
        s = (a0 + a1) + (a2 + a3);
      }
      sh_pre[wave][lane] = s;
    }
    __syncthreads();
    if (tid < 64) {
      float r  = fast_sigmoid(sh_pre[0][tid]);
      float ig = fast_sigmoid(sh_pre[1][tid]);
      float n  = fast_tanh(sh_pre[3][tid] + r * sh_pre[2][tid]);
      float hnew = (1.0f - ig) * n + ig * sh_hid[tid];
      sh_hid[tid] = hnew;
      sh_hist[t * 64 + tid] = hnew;
    }
    __syncthreads();

    // ---- wave-specialized tail (t<14): hs+tree-barrier / hr ----
    if (t < 14) {
      if (wave <= 1) {
        const int m = tid;  // 0..127
        const ushort4* wp = ((const ushort4*)lds_w1t) + m;
        const float4* h4 = (const float4*)sh_hid;
        float a0 = 0.f, a1 = 0.f, a2 = 0.f, a3 = 0.f;
#pragma unroll
        for (int c = 0; c < 16; ++c) {
          ushort4 wv = wp[c << 7];
          float4 hv = h4[c];
          a0 += hv.x * b2f(wv.x); a1 += hv.y * b2f(wv.y);
          a2 += hv.z * b2f(wv.z); a3 += hv.w * b2f(wv.w);
        }
        float s = ((a0 + a1) + (a2 + a3)) * CSCALE;
        float hi = __shfl_down(s, 1);
        if (!(lane & 1))
          st_coh_u32((unsigned*)hs_nxt + (row << 6) + (m >> 1), pack_bf2(s, hi));
        asm volatile("s_waitcnt vmcnt(0)" ::: "memory");
        if (lane == 0) atomicAdd(&sh_w01, 1);
        if (wave == 0 && lane == 0) {
          const int tgt = t + 1;
          while (__hip_atomic_load(&sh_w01, __ATOMIC_RELAXED, __HIP_MEMORY_SCOPE_WORKGROUP) < 2 * tgt) {}
          const int bt = b * 15 + t;
          int* leaf = sync + ((bt << 3) + (j & 7)) * 32;
          int* root = sync + SYNC_ROOT + bt * 32;
          int* flag = sync + SYNC_FLAG + bt * 32;
          int r = __hip_atomic_fetch_add(leaf, 1, __ATOMIC_RELAXED, __HIP_MEMORY_SCOPE_AGENT);
          if (r == 15) {
            int r2 = __hip_atomic_fetch_add(root, 1, __ATOMIC_RELAXED, __HIP_MEMORY_SCOPE_AGENT);
            if (r2 == 7)
              __hip_atomic_store(flag, 1, __ATOMIC_RELAXED, __HIP_MEMORY_SCOPE_AGENT);
          }
          while (__hip_atomic_load(flag, __ATOMIC_RELAXED, __HIP_MEMORY_SCOPE_AGENT) == 0)
            __builtin_amdgcn_s_sleep(1);
        }
      } else if (wave == 2) {
        const int4* wp1 = (const int4*)(bw + BW1RT + (lane << 6));
        const int4* wp2 = (const int4*)(bw + BW1RT + ((lane + 64) << 6));
        const float4* h4 = (const float4*)sh_hid;
        float s1a = bm1a, s1b = 0.f, s2a = bm1b, s2b = 0.f;
#pragma unroll
        for (int c = 0; c < 8; ++c) {
          ldu u1, u2; u1.q = wp1[c]; u2.q = wp2[c];
          float4 h0 = h4[2 * c], h1 = h4[2 * c + 1];
          s1a += h0.x * b2f(u1.s[0]); s1b += h0.y * b2f(u1.s[1]);
          s1a += h0.z * b2f(u1.s[2]); s1b += h0.w * b2f(u1.s[3]);
          s1a += h1.x * b2f(u1.s[4]); s1b += h1.y * b2f(u1.s[5]);
          s1a += h1.z * b2f(u1.s[6]); s1b += h1.w * b2f(u1.s[7]);
          s2a += h0.x * b2f(u2.s[0]); s2b += h0.y * b2f(u2.s[1]);
          s2a += h0.z * b2f(u2.s[2]); s2b += h0.w * b2f(u2.s[3]);
          s2a += h1.x * b2f(u2.s[4]); s2b += h1.y * b2f(u2.s[5]);
          s2a += h1.z * b2f(u2.s[6]); s2b += h1.w * b2f(u2.s[7]);
        }
        sh_hr[lane] = (s1a + s1b) * CSCALE;
        sh_hr[lane + 64] = (s2a + s2b) * CSCALE;
      }
      // waves 3-7: idle until barrier
    }
    __syncthreads();
  }

  // ---- post-loop: restage O1|O2|O3 into lds_gate_t (gates dead), then 8-wave MLP ----
  for (int i = tid; i < 8192; i += 512) {    // O1,O2: [o][c][h][s]
    int o = i >> 12, r = i & 4095, c = r >> 8, rem = r & 255, h = rem >> 2, s = rem & 3;
    lds_gate_t[i] = bw[BWO1 + (o << 12) + (((c << 2) + s) << 6) + h];
  }
  for (int i = tid; i < 1024; i += 512) {    // O3: [c][d][s]
    int c = i >> 6, rem = i & 63, d = rem >> 2, s = rem & 3;
    lds_gate_t[8192 + i] = bw[BWO3 + (((c << 2) + s) << 4) + d];
  }
  __syncthreads();

#pragma unroll
  for (int it = 0; it < 2; ++it) {
    const int tt = wave + (it << 3);
    if (tt >= 15) continue;  // wave-uniform
    const float4* h4 = (const float4*)(sh_hist + tt * 64);
    {
      const ushort4* r1 = ((const ushort4*)lds_gate_t) + lane;
      float a0 = bo1, a1 = 0.f, a2 = 0.f, a3 = 0.f;
#pragma unroll
      for (int c = 0; c < 16; ++c) {
        ushort4 wv = r1[c << 6]; float4 hv = h4[c];
        a0 += hv.x * b2f(wv.x); a1 += hv.y * b2f(wv.y);
        a2 += hv.z * b2f(wv.z); a3 += hv.w * b2f(wv.w);
      }
      sh_pre[wave][lane] = fmaxf((a0 + a1) + (a2 + a3), 0.0f);
    }
    {
      const ushort4* r2 = ((const ushort4*)lds_gate_t) + 1024 + lane;
      const float4* p4 = (const float4*)sh_pre[wave];
      float a0 = bo2, a1 = 0.f, a2 = 0.f, a3 = 0.f;
#pragma unroll
      for (int c = 0; c < 16; ++c) {
        ushort4 wv = r2[c << 6]; float4 pv = p4[c];
        a0 += pv.x * b2f(wv.x); a1 += pv.y * b2f(wv.y);
        a2 += pv.z * b2f(wv.z); a3 += pv.w * b2f(wv.w);
      }
      sh_aggw[wave][lane] = fmaxf((a0 + a1) + (a2 + a3), 0.0f);
    }
    if (lane < 16) {
      const ushort4* r3 = ((const ushort4*)lds_gate_t) + 2048 + lane;
      const float4* q4 = (const float4*)sh_aggw[wave];
      float a0 = bo3, a1 = 0.f, a2 = 0.f, a3 = 0.f;
#pragma unroll
      for (int c = 0; c < 16; ++c) {
        ushort4 wv = r3[c << 4]; float4 qv = q4[c];
        a0 += qv.x * b2f(wv.x); a1 += qv.y * b2f(wv.y);
        a2 += qv.z * b2f(wv.z); a3 += qv.w * b2f(wv.w);
      }
      float pred = sh_xall[(tt << 4) + lane] + (a0 + a1) + (a2 + a3);
      out[((b * 15 + tt) * 128 + j) * 16 + lane] = pred;
      float d = sh_xall[((tt + 1) << 4) + lane] - pred;
      macc += d * d;
    }
  }
  macc += __shfl_xor(macc, 1);
  macc += __shfl_xor(macc, 2);
  macc += __shfl_xor(macc, 4);
  macc += __shfl_xor(macc, 8);
  __syncthreads();
  if (lane == 0) sh_agg[wave] = macc;
  __syncthreads();
  if (tid == 0) {
    float s = 0.0f;
#pragma unroll
    for (int w = 0; w < 8; ++w) s += sh_agg[w];
    ws[OFF_PART + bj] = s;
  }
}

// ---------------- finalize: loglik ----------------
__global__ void final_kernel(const float* __restrict__ log_sigma, const float* __restrict__ ws,
                             float* __restrict__ out) {
  __shared__ float red[256];
  const int tid = threadIdx.x;
  red[tid] = ws[OFF_PART + tid] + ws[OFF_PART + 256 + tid];
  __syncthreads();
  if (tid == 0) {
    float mse = 0.0f;
    for (int i = 0; i < 256; ++i) mse += red[i];
    float sigma = expf(log_sigma[0]);
    float cst = 8192.0f * logf(sigma * sqrtf(6.2831853071795864f));  // N*D*B
    out[122880] = -(mse / (2.0f * sigma * sigma) + 15.0f * cst);
  }
}

extern "C" void kernel_launch(void* const* d_in, const int* in_sizes, int n_in,
                              void* d_out, int out_size, void* d_ws, size_t ws_size,
                              hipStream_t stream) {
  (void)in_sizes; (void)n_in; (void)out_size; (void)ws_size;
  const float* A      = (const float*)d_in[0];
  const float* X      = (const float*)d_in[1];
  const float* W_msg1 = (const float*)d_in[2];
  const float* b_msg1 = (const float*)d_in[3];
  const float* W_msg2 = (const float*)d_in[4];
  const float* b_msg2 = (const float*)d_in[5];
  const float* W_ir   = (const float*)d_in[6];
  const float* b_ir   = (const float*)d_in[7];
  const float* W_ii   = (const float*)d_in[8];
  const float* b_ii   = (const float*)d_in[9];
  const float* W_in   = (const float*)d_in[10];
  const float* b_in   = (const float*)d_in[11];
  const float* W_hr   = (const float*)d_in[12];
  const float* W_hi   = (const float*)d_in[13];
  const float* W_hh   = (const float*)d_in[14];
  const float* W_o1   = (const float*)d_in[15];
  const float* b_o1   = (const float*)d_in[16];
  const float* W_o2   = (const float*)d_in[17];
  const float* b_o2   = (const float*)d_in[18];
  const float* W_o3   = (const float*)d_in[19];
  const float* b_o3   = (const float*)d_in[20];
  const float* log_sigma = (const float*)d_in[21];
  float* ws  = (float*)d_ws;
  float* out = (float*)d_out;

  init_kernel<<<(INIT_TOTAL + 255) / 256, 256, 0, stream>>>(
      W_msg2, W_ir, W_ii, W_in, W_hr, W_hi, W_hh, W_o1, W_o2, W_o3, W_msg1, ws);
  step_all_kernel<<<NBLK, 512, 0, stream>>>(A, X, b_msg1, b_msg2, b_ir, b_ii, b_in,
                                            b_o1, b_o2, b_o3, ws, out);
  final_kernel<<<1, 256, 0, stream>>>(log_sigma, ws, out);
}